// Round 2
// baseline (3568.874 us; speedup 1.0000x reference)
//
#include <hip/hip_runtime.h>
#include <math.h>

typedef _Float16 f16;
typedef _Float16 f16x8 __attribute__((ext_vector_type(8)));
typedef float f32x4 __attribute__((ext_vector_type(4)));

#define B_ 4
#define S_ 1024
#define H_ 1280
#define NH_ 20
#define DH_ 64
#define I_ 5120
#define C_ 13
#define P_ 8

__device__ __forceinline__ void store_val(float* p, float v) { *p = v; }
__device__ __forceinline__ void store_val(f16* p, float v) { *p = (f16)v; }

// ---------------------------------------------------------------------------
// Crosstalk: R = out1 @ out2  (8x8), tiny, one block
// ---------------------------------------------------------------------------
__global__ void crosstalk_kernel(const float* __restrict__ Mg,
                                 const float* __restrict__ W1, const float* __restrict__ b1,
                                 const float* __restrict__ W2, const float* __restrict__ b2,
                                 float* __restrict__ Rg) {
    __shared__ float o1[P_][C_];
    __shared__ float o2[C_][P_];
    int t = threadIdx.x;
    if (t < P_ * C_) {
        int p = t / C_, c = t % C_;
        float s = b1[p];
        for (int k = 0; k < C_; k++) s += Mg[k * C_ + c] * W1[p * C_ + k];
        o1[p][c] = s;
        int c2 = t / P_, p2 = t % P_;   // 104 = 13*8 covers (c2,p2)
        float s2 = b2[p2];
        for (int k = 0; k < C_; k++) s2 += Mg[c2 * C_ + k] * W2[p2 * C_ + k];
        o2[c2][p2] = s2;
    }
    __syncthreads();
    if (t < P_ * P_) {
        int p = t >> 3, q = t & 7;
        float s = 0.f;
        for (int c = 0; c < C_; c++) s += o1[p][c] * o2[c][q];
        Rg[t] = s;
    }
}

// ---------------------------------------------------------------------------
// ptm = softmax(h @ W_ptm^T + b_ptm); t = ptm @ R.  One wave per token row.
// ---------------------------------------------------------------------------
__global__ __launch_bounds__(256) void ptm_kernel(const float* __restrict__ hin,
                                                  const float* __restrict__ Wptm,
                                                  const float* __restrict__ bptm,
                                                  const float* __restrict__ Rg,
                                                  float* __restrict__ ptm,
                                                  float* __restrict__ tg) {
    int wv = threadIdx.x >> 6, lane = threadIdx.x & 63;
    int row = blockIdx.x * 4 + wv;
    const float* hrow = hin + (size_t)row * H_;
    float acc[P_] = {};
    for (int i = 0; i < H_ / 64; i++) {
        int k = lane + 64 * i;
        float hv = hrow[k];
#pragma unroll
        for (int p = 0; p < P_; p++) acc[p] += hv * Wptm[p * H_ + k];
    }
#pragma unroll
    for (int p = 0; p < P_; p++) {
#pragma unroll
        for (int o = 32; o >= 1; o >>= 1) acc[p] += __shfl_xor(acc[p], o);
        acc[p] += bptm[p];
    }
    float mx = acc[0];
#pragma unroll
    for (int p = 1; p < P_; p++) mx = fmaxf(mx, acc[p]);
    float sum = 0.f;
#pragma unroll
    for (int p = 0; p < P_; p++) { acc[p] = expf(acc[p] - mx); sum += acc[p]; }
    float rinv = 1.f / sum;
#pragma unroll
    for (int p = 0; p < P_; p++) acc[p] *= rinv;
    float tv[P_];
#pragma unroll
    for (int d = 0; d < P_; d++) {
        float s = 0.f;
#pragma unroll
        for (int c = 0; c < P_; c++) s += acc[c] * Rg[c * P_ + d];
        tv[d] = s;
    }
    if (lane == 0) {
#pragma unroll
        for (int p = 0; p < P_; p++) {
            ptm[(size_t)row * P_ + p] = acc[p];
            tg[(size_t)row * P_ + p]  = tv[p];
        }
    }
}

// ---------------------------------------------------------------------------
// GEMM: Y[M,N] = X[M,K] @ W[N,K]^T + bias, MFMA f16 16x16x32, f32 accumulate.
// XT = float (convert at staging) or f16 (direct). W always f32.
// MODE 0: plain. MODE 1: exact GELU. MODE 2: + residual (f16 res).
// 64x64 tile, BK=32, LDS stride 40, 4 waves in 2x2.
// ---------------------------------------------------------------------------
template <int MODE, typename XT, typename YT>
__global__ __launch_bounds__(256) void gemm_kernel(const XT* __restrict__ X,
                                                   const float* __restrict__ W,
                                                   const float* __restrict__ bias,
                                                   YT* __restrict__ Y,
                                                   const f16* __restrict__ res,
                                                   int Mdim, int Ndim, int Kdim) {
    __shared__ f16 sA[64 * 40];
    __shared__ f16 sB[64 * 40];
    const int t = threadIdx.x;
    const int m0 = blockIdx.x * 64, n0 = blockIdx.y * 64;
    const int lane = t & 63, w = t >> 6;
    const int wr = w >> 1, wc = w & 1;
    const int lrow = lane & 15, kq = lane >> 4;

    f32x4 acc[2][2] = {};
    const int r = t >> 2, c = t & 3;
    const XT* gA = X + (size_t)(m0 + r) * Kdim + c * 8;
    const float* gB = W + (size_t)(n0 + r) * Kdim + c * 8;

    for (int k0 = 0; k0 < Kdim; k0 += 32) {
        f16x8 ha, hb;
        if constexpr (__is_same(XT, float)) {
            f32x4 a0 = *(const f32x4*)(gA + k0);
            f32x4 a1 = *(const f32x4*)(gA + k0 + 4);
#pragma unroll
            for (int e = 0; e < 4; e++) { ha[e] = (f16)a0[e]; ha[4 + e] = (f16)a1[e]; }
        } else {
            ha = *(const f16x8*)(gA + k0);
        }
        {
            f32x4 b0 = *(const f32x4*)(gB + k0);
            f32x4 b1 = *(const f32x4*)(gB + k0 + 4);
#pragma unroll
            for (int e = 0; e < 4; e++) { hb[e] = (f16)b0[e]; hb[4 + e] = (f16)b1[e]; }
        }
        *(f16x8*)&sA[r * 40 + c * 8] = ha;
        *(f16x8*)&sB[r * 40 + c * 8] = hb;
        __syncthreads();
        f16x8 af[2], bfr[2];
#pragma unroll
        for (int i = 0; i < 2; i++) af[i] = *(const f16x8*)&sA[(32 * wr + 16 * i + lrow) * 40 + kq * 8];
#pragma unroll
        for (int j = 0; j < 2; j++) bfr[j] = *(const f16x8*)&sB[(32 * wc + 16 * j + lrow) * 40 + kq * 8];
#pragma unroll
        for (int i = 0; i < 2; i++)
#pragma unroll
            for (int j = 0; j < 2; j++)
                acc[i][j] = __builtin_amdgcn_mfma_f32_16x16x32_f16(af[i], bfr[j], acc[i][j], 0, 0, 0);
        __syncthreads();
    }
    // D layout: col = lane&15, row = (lane>>4)*4 + reg
#pragma unroll
    for (int i = 0; i < 2; i++) {
#pragma unroll
        for (int j = 0; j < 2; j++) {
            int col = n0 + 32 * wc + 16 * j + lrow;
            float bcol = bias[col];
#pragma unroll
            for (int rr = 0; rr < 4; rr++) {
                int row = m0 + 32 * wr + 16 * i + kq * 4 + rr;
                float v = acc[i][j][rr] + bcol;
                if (MODE == 1) v = 0.5f * v * (1.0f + erff(v * 0.70710678118654752f));
                if (MODE == 2) v += (float)res[(size_t)row * Ndim + col];
                store_val(&Y[(size_t)row * Ndim + col], v);
            }
        }
    }
}

// ---------------------------------------------------------------------------
// Attention: block = (8 q-rows, head h, batch b). Scores (incl. tanh bilinear
// bias + mask) in LDS -> softmax -> P@V. Writes xpre = h + ctx (fp32).
// ---------------------------------------------------------------------------
__global__ __launch_bounds__(256) void attn_kernel(const f16* __restrict__ q,
                                                   const f16* __restrict__ k,
                                                   const f16* __restrict__ v,
                                                   const float* __restrict__ ptm,
                                                   const float* __restrict__ tg,
                                                   const float* __restrict__ mask,
                                                   const float* __restrict__ bscale_p,
                                                   const float* __restrict__ hin,
                                                   float* __restrict__ xpre) {
    __shared__ float sc[8][S_];      // 32 KB score rows
    __shared__ float kv[64][64];     // 16 KB K/V tile
    __shared__ float qf[8][64];
    __shared__ float tl[8][8];
    __shared__ float pmt[64][8];
    __shared__ float red[8][64];

    const int t = threadIdx.x;
    const int l0 = blockIdx.x * 8, h = blockIdx.y, b = blockIdx.z;
    const float bscale = bscale_p[0];
    const size_t base = (size_t)b * S_ * H_ + (size_t)h * DH_;

    for (int idx = t; idx < 8 * 64; idx += 256) {
        int l = idx >> 6, d = idx & 63;
        qf[l][d] = (float)q[base + (size_t)(l0 + l) * H_ + d] * 0.125f;  // 1/sqrt(64)
    }
    if (t < 64) { int l = t >> 3, p = t & 7; tl[l][p] = tg[((size_t)b * S_ + l0 + l) * P_ + p]; }
    __syncthreads();

    const int sl = t >> 5, ms = t & 31;
    float4 qc[16];
    float tr[8];
#pragma unroll
    for (int cc = 0; cc < 16; cc++) qc[cc] = *(const float4*)&qf[sl][cc * 4];
#pragma unroll
    for (int p = 0; p < P_; p++) tr[p] = tl[sl][p];

    // ---- pass 1: scores ----
    for (int mt = 0; mt < 16; mt++) {
        int m0 = mt * 64;
        for (int idx = t; idx < 512; idx += 256) {   // 64 rows x 8 chunks of 8 halves
            int mm = idx >> 3, d8 = (idx & 7) * 8;
            f16x8 raw = *(const f16x8*)&k[base + (size_t)(m0 + mm) * H_ + d8];
#pragma unroll
            for (int e = 0; e < 8; e++) kv[mm][d8 + e] = (float)raw[e];
        }
        for (int idx = t; idx < 64 * 8; idx += 256) {
            int mm = idx >> 3, p = idx & 7;
            pmt[mm][p] = ptm[((size_t)b * S_ + m0 + mm) * P_ + p];
        }
        __syncthreads();
#pragma unroll
        for (int u = 0; u < 2; u++) {
            int m = ms + 32 * u;
            float dot = 0.f;
#pragma unroll
            for (int cc = 0; cc < 16; cc++) {
                float4 kk = *(const float4*)&kv[m][cc * 4];
                float4 qq = qc[cc];
                dot += qq.x * kk.x + qq.y * kk.y + qq.z * kk.z + qq.w * kk.w;
            }
            float bb = 0.f;
#pragma unroll
            for (int p = 0; p < P_; p++) bb += tr[p] * pmt[m][p];
            float mval = mask[(size_t)b * S_ + m0 + m];
            sc[sl][m0 + m] = dot + tanhf(bb) * bscale + (1.0f - mval) * (-3.4028235e38f);
        }
        __syncthreads();
    }

    // ---- softmax (each wave owns 2 rows) ----
    const int wv = t >> 6, lane = t & 63;
    for (int li = 0; li < 2; li++) {
        int l = wv * 2 + li;
        float mx = -3.4028235e38f;
#pragma unroll
        for (int i = 0; i < 16; i++) mx = fmaxf(mx, sc[l][lane + 64 * i]);
#pragma unroll
        for (int o = 32; o >= 1; o >>= 1) mx = fmaxf(mx, __shfl_xor(mx, o));
        float sum = 0.f;
#pragma unroll
        for (int i = 0; i < 16; i++) {
            float e = expf(sc[l][lane + 64 * i] - mx);
            sc[l][lane + 64 * i] = e;
            sum += e;
        }
#pragma unroll
        for (int o = 32; o >= 1; o >>= 1) sum += __shfl_xor(sum, o);
        float rinv = 1.0f / sum;
#pragma unroll
        for (int i = 0; i < 16; i++) sc[l][lane + 64 * i] *= rinv;
    }
    __syncthreads();

    // ---- pass 2: ctx = P @ V ----
    const int pl = t >> 5, rest = t & 31, dc = (rest & 15) * 4, half = rest >> 4;
    float4 acc = {0.f, 0.f, 0.f, 0.f};
    for (int mt = 0; mt < 16; mt++) {
        int m0 = mt * 64;
        for (int idx = t; idx < 512; idx += 256) {
            int mm = idx >> 3, d8 = (idx & 7) * 8;
            f16x8 raw = *(const f16x8*)&v[base + (size_t)(m0 + mm) * H_ + d8];
#pragma unroll
            for (int e = 0; e < 8; e++) kv[mm][d8 + e] = (float)raw[e];
        }
        __syncthreads();
        for (int mm = half * 32; mm < half * 32 + 32; mm++) {
            float pw = sc[pl][m0 + mm];
            float4 vv = *(const float4*)&kv[mm][dc];
            acc.x += pw * vv.x; acc.y += pw * vv.y; acc.z += pw * vv.z; acc.w += pw * vv.w;
        }
        __syncthreads();
    }
    if (half == 0) *(float4*)&red[pl][dc] = acc;
    __syncthreads();
    if (half == 1) {
        float4 o = *(const float4*)&red[pl][dc];
        o.x += acc.x; o.y += acc.y; o.z += acc.z; o.w += acc.w;
        size_t obase = base + (size_t)(l0 + pl) * H_ + dc;
        o.x += hin[obase + 0]; o.y += hin[obase + 1];
        o.z += hin[obase + 2]; o.w += hin[obase + 3];
        *(float4*)&xpre[obase] = o;
    }
}

// ---------------------------------------------------------------------------
// LayerNorm over H=1280; one block per row. fp32 in, f16 out.
// ---------------------------------------------------------------------------
__global__ __launch_bounds__(256) void ln_kernel(const float* __restrict__ xpre,
                                                 const float* __restrict__ g,
                                                 const float* __restrict__ bb,
                                                 f16* __restrict__ xln) {
    int row = blockIdx.x, t = threadIdx.x;
    const float* xr = xpre + (size_t)row * H_;
    float xv[5], s1 = 0.f, s2 = 0.f;
#pragma unroll
    for (int i = 0; i < 5; i++) {
        float v = xr[t + 256 * i];
        xv[i] = v; s1 += v; s2 += v * v;
    }
#pragma unroll
    for (int o = 32; o >= 1; o >>= 1) { s1 += __shfl_xor(s1, o); s2 += __shfl_xor(s2, o); }
    __shared__ float r1[4], r2[4];
    int wv = t >> 6, lane = t & 63;
    if (lane == 0) { r1[wv] = s1; r2[wv] = s2; }
    __syncthreads();
    float m1 = (r1[0] + r1[1] + r1[2] + r1[3]) * (1.0f / H_);
    float m2 = (r2[0] + r2[1] + r2[2] + r2[3]) * (1.0f / H_);
    float rstd = rsqrtf(m2 - m1 * m1 + 1e-5f);
#pragma unroll
    for (int i = 0; i < 5; i++) {
        int c = t + 256 * i;
        float v = (xv[i] - m1) * rstd * g[c] + bb[c];
        xln[(size_t)row * H_ + c] = (f16)v;
    }
}

// ---------------------------------------------------------------------------
extern "C" void kernel_launch(void* const* d_in, const int* in_sizes, int n_in,
                              void* d_out, int out_size, void* d_ws, size_t ws_size,
                              hipStream_t stream) {
    (void)in_sizes; (void)n_in; (void)out_size; (void)ws_size;
    const float* hin  = (const float*)d_in[0];
    const float* mask = (const float*)d_in[1];
    const float* Wq = (const float*)d_in[2];  const float* bq = (const float*)d_in[3];
    const float* Wk = (const float*)d_in[4];  const float* bk = (const float*)d_in[5];
    const float* Wv = (const float*)d_in[6];  const float* bv = (const float*)d_in[7];
    const float* Wct1 = (const float*)d_in[8];  const float* bct1 = (const float*)d_in[9];
    const float* Wct2 = (const float*)d_in[10]; const float* bct2 = (const float*)d_in[11];
    const float* Mg = (const float*)d_in[12];   const float* bscale = (const float*)d_in[13];
    const float* Wptm = (const float*)d_in[14]; const float* bptm = (const float*)d_in[15];
    const float* lng = (const float*)d_in[16];  const float* lnb = (const float*)d_in[17];
    const float* Wf1 = (const float*)d_in[18];  const float* bf1 = (const float*)d_in[19];
    const float* Wf2 = (const float*)d_in[20];  const float* bf2 = (const float*)d_in[21];

    // workspace (peak ~60.3 MB; g1 aliases dead qkv+xpre region)
    char* ws = (char*)d_ws;
    const size_t SZ_PT  = (size_t)B_ * S_ * P_ * 4;       // 131072
    const size_t SZ_H16 = (size_t)B_ * S_ * H_ * 2;       // 10485760 (f16)
    const size_t SZ_H32 = (size_t)B_ * S_ * H_ * 4;       // 20971520 (f32)
    float* Rg   = (float*)(ws);
    float* ptm  = (float*)(ws + 256);
    float* tg   = (float*)(ws + 256 + SZ_PT);
    char* A0    = ws + 256 + 2 * SZ_PT;                   // 262400, 16-aligned
    f16* qb     = (f16*)(A0);
    f16* kb     = (f16*)(A0 + SZ_H16);
    f16* vb     = (f16*)(A0 + 2 * SZ_H16);
    float* xpre = (float*)(A0 + 3 * SZ_H16);
    f16* xln    = (f16*)(A0 + 3 * SZ_H16 + SZ_H32);       // after alias region
    f16* g1     = (f16*)(A0);  // 41.9 MB, aliases qkv(31.4)+xpre(21.0): both dead by FFN1

    crosstalk_kernel<<<1, 128, 0, stream>>>(Mg, Wct1, bct1, Wct2, bct2, Rg);
    ptm_kernel<<<S_ * B_ / 4, 256, 0, stream>>>(hin, Wptm, bptm, Rg, ptm, tg);
    gemm_kernel<0, float, f16><<<dim3(64, 20), 256, 0, stream>>>(hin, Wq, bq, qb, nullptr, B_ * S_, H_, H_);
    gemm_kernel<0, float, f16><<<dim3(64, 20), 256, 0, stream>>>(hin, Wk, bk, kb, nullptr, B_ * S_, H_, H_);
    gemm_kernel<0, float, f16><<<dim3(64, 20), 256, 0, stream>>>(hin, Wv, bv, vb, nullptr, B_ * S_, H_, H_);
    attn_kernel<<<dim3(S_ / 8, NH_, B_), 256, 0, stream>>>(qb, kb, vb, ptm, tg, mask, bscale, hin, xpre);
    ln_kernel<<<B_ * S_, 256, 0, stream>>>(xpre, lng, lnb, xln);
    gemm_kernel<1, f16, f16><<<dim3(64, I_ / 64), 256, 0, stream>>>(xln, Wf1, bf1, g1, nullptr, B_ * S_, I_, H_);
    gemm_kernel<2, f16, float><<<dim3(64, 20), 256, 0, stream>>>(g1, Wf2, bf2, (float*)d_out, xln, B_ * S_, H_, I_);
}

// Round 3
// 743.690 us; speedup vs baseline: 4.7989x; 4.7989x over previous
//
#include <hip/hip_runtime.h>
#include <math.h>

typedef _Float16 f16;
typedef _Float16 f16x8 __attribute__((ext_vector_type(8)));
typedef float f32x4 __attribute__((ext_vector_type(4)));

#define B_ 4
#define S_ 1024
#define H_ 1280
#define NH_ 20
#define DH_ 64
#define I_ 5120
#define C_ 13
#define P_ 8

__device__ __forceinline__ void store_val(float* p, float v) { *p = v; }
__device__ __forceinline__ void store_val(f16* p, float v) { *p = (f16)v; }

// ---------------------------------------------------------------------------
// Crosstalk: R = out1 @ out2  (8x8), tiny, one block
// ---------------------------------------------------------------------------
__global__ void crosstalk_kernel(const float* __restrict__ Mg,
                                 const float* __restrict__ W1, const float* __restrict__ b1,
                                 const float* __restrict__ W2, const float* __restrict__ b2,
                                 float* __restrict__ Rg) {
    __shared__ float o1[P_][C_];
    __shared__ float o2[C_][P_];
    int t = threadIdx.x;
    if (t < P_ * C_) {
        int p = t / C_, c = t % C_;
        float s = b1[p];
        for (int k = 0; k < C_; k++) s += Mg[k * C_ + c] * W1[p * C_ + k];
        o1[p][c] = s;
        int c2 = t / P_, p2 = t % P_;
        float s2 = b2[p2];
        for (int k = 0; k < C_; k++) s2 += Mg[c2 * C_ + k] * W2[p2 * C_ + k];
        o2[c2][p2] = s2;
    }
    __syncthreads();
    if (t < P_ * P_) {
        int p = t >> 3, q = t & 7;
        float s = 0.f;
        for (int c = 0; c < C_; c++) s += o1[p][c] * o2[c][q];
        Rg[t] = s;
    }
}

// ---------------------------------------------------------------------------
// ptm = softmax(h @ W_ptm^T + b_ptm); t = ptm @ R.  One wave per token row.
// ---------------------------------------------------------------------------
__global__ __launch_bounds__(256) void ptm_kernel(const float* __restrict__ hin,
                                                  const float* __restrict__ Wptm,
                                                  const float* __restrict__ bptm,
                                                  const float* __restrict__ Rg,
                                                  float* __restrict__ ptm,
                                                  float* __restrict__ tg) {
    int wv = threadIdx.x >> 6, lane = threadIdx.x & 63;
    int row = blockIdx.x * 4 + wv;
    const float* hrow = hin + (size_t)row * H_;
    float acc[P_] = {};
    for (int i = 0; i < H_ / 64; i++) {
        int k = lane + 64 * i;
        float hv = hrow[k];
#pragma unroll
        for (int p = 0; p < P_; p++) acc[p] += hv * Wptm[p * H_ + k];
    }
#pragma unroll
    for (int p = 0; p < P_; p++) {
#pragma unroll
        for (int o = 32; o >= 1; o >>= 1) acc[p] += __shfl_xor(acc[p], o);
        acc[p] += bptm[p];
    }
    float mx = acc[0];
#pragma unroll
    for (int p = 1; p < P_; p++) mx = fmaxf(mx, acc[p]);
    float sum = 0.f;
#pragma unroll
    for (int p = 0; p < P_; p++) { acc[p] = expf(acc[p] - mx); sum += acc[p]; }
    float rinv = 1.f / sum;
#pragma unroll
    for (int p = 0; p < P_; p++) acc[p] *= rinv;
    float tv[P_];
#pragma unroll
    for (int d = 0; d < P_; d++) {
        float s = 0.f;
#pragma unroll
        for (int c = 0; c < P_; c++) s += acc[c] * Rg[c * P_ + d];
        tv[d] = s;
    }
    if (lane == 0) {
#pragma unroll
        for (int p = 0; p < P_; p++) {
            ptm[(size_t)row * P_ + p] = acc[p];
            tg[(size_t)row * P_ + p]  = tv[p];
        }
    }
}

// ---------------------------------------------------------------------------
// Bias precompute: bb[b][l][m] = tanh(dot8(t[b,l], ptm[b,m]))*bscale
//                               + (1-mask[b,m])*(-30000)   (f16 out)
// One block per (b,l); 256 threads x 4 m.
// ---------------------------------------------------------------------------
__global__ __launch_bounds__(256) void bias_kernel(const float* __restrict__ tg,
                                                   const float* __restrict__ ptm,
                                                   const float* __restrict__ mask,
                                                   const float* __restrict__ bscale_p,
                                                   f16* __restrict__ bb) {
    const int bl = blockIdx.x;          // b*1024 + l
    const int b = bl >> 10;
    const int t = threadIdx.x;
    __shared__ float tl[P_];
    if (t < P_) tl[t] = tg[(size_t)bl * P_ + t];
    __syncthreads();
    const float bscale = bscale_p[0];
    float t0 = tl[0], t1 = tl[1], t2 = tl[2], t3 = tl[3];
    float t4 = tl[4], t5 = tl[5], t6 = tl[6], t7 = tl[7];
#pragma unroll
    for (int i = 0; i < 4; i++) {
        int m = t + 256 * i;
        const float* pm = ptm + ((size_t)b * S_ + m) * P_;
        float4 p0 = *(const float4*)pm;
        float4 p1 = *(const float4*)(pm + 4);
        float d = t0 * p0.x + t1 * p0.y + t2 * p0.z + t3 * p0.w
                + t4 * p1.x + t5 * p1.y + t6 * p1.z + t7 * p1.w;
        float v = tanhf(d) * bscale + (1.0f - mask[(size_t)b * S_ + m]) * (-30000.0f);
        bb[(size_t)bl * S_ + m] = (f16)v;
    }
}

// ---------------------------------------------------------------------------
// GEMM: Y[M,N] = X[M,K] @ W[N,K]^T + bias, MFMA f16 16x16x32, f32 accumulate.
// MODE 0: plain. MODE 1: exact GELU. MODE 2: + residual (f16 res).
// ---------------------------------------------------------------------------
template <int MODE, typename XT, typename YT>
__global__ __launch_bounds__(256) void gemm_kernel(const XT* __restrict__ X,
                                                   const float* __restrict__ W,
                                                   const float* __restrict__ bias,
                                                   YT* __restrict__ Y,
                                                   const f16* __restrict__ res,
                                                   int Mdim, int Ndim, int Kdim) {
    __shared__ f16 sA[64 * 40];
    __shared__ f16 sB[64 * 40];
    const int t = threadIdx.x;
    const int m0 = blockIdx.x * 64, n0 = blockIdx.y * 64;
    const int lane = t & 63, w = t >> 6;
    const int wr = w >> 1, wc = w & 1;
    const int lrow = lane & 15, kq = lane >> 4;

    f32x4 acc[2][2] = {};
    const int r = t >> 2, c = t & 3;
    const XT* gA = X + (size_t)(m0 + r) * Kdim + c * 8;
    const float* gB = W + (size_t)(n0 + r) * Kdim + c * 8;

    for (int k0 = 0; k0 < Kdim; k0 += 32) {
        f16x8 ha, hb;
        if constexpr (__is_same(XT, float)) {
            f32x4 a0 = *(const f32x4*)(gA + k0);
            f32x4 a1 = *(const f32x4*)(gA + k0 + 4);
#pragma unroll
            for (int e = 0; e < 4; e++) { ha[e] = (f16)a0[e]; ha[4 + e] = (f16)a1[e]; }
        } else {
            ha = *(const f16x8*)(gA + k0);
        }
        {
            f32x4 b0 = *(const f32x4*)(gB + k0);
            f32x4 b1 = *(const f32x4*)(gB + k0 + 4);
#pragma unroll
            for (int e = 0; e < 4; e++) { hb[e] = (f16)b0[e]; hb[4 + e] = (f16)b1[e]; }
        }
        *(f16x8*)&sA[r * 40 + c * 8] = ha;
        *(f16x8*)&sB[r * 40 + c * 8] = hb;
        __syncthreads();
        f16x8 af[2], bfr[2];
#pragma unroll
        for (int i = 0; i < 2; i++) af[i] = *(const f16x8*)&sA[(32 * wr + 16 * i + lrow) * 40 + kq * 8];
#pragma unroll
        for (int j = 0; j < 2; j++) bfr[j] = *(const f16x8*)&sB[(32 * wc + 16 * j + lrow) * 40 + kq * 8];
#pragma unroll
        for (int i = 0; i < 2; i++)
#pragma unroll
            for (int j = 0; j < 2; j++)
                acc[i][j] = __builtin_amdgcn_mfma_f32_16x16x32_f16(af[i], bfr[j], acc[i][j], 0, 0, 0);
        __syncthreads();
    }
#pragma unroll
    for (int i = 0; i < 2; i++) {
#pragma unroll
        for (int j = 0; j < 2; j++) {
            int col = n0 + 32 * wc + 16 * j + lrow;
            float bcol = bias[col];
#pragma unroll
            for (int rr = 0; rr < 4; rr++) {
                int row = m0 + 32 * wr + 16 * i + kq * 4 + rr;
                float v = acc[i][j][rr] + bcol;
                if (MODE == 1) v = 0.5f * v * (1.0f + erff(v * 0.70710678118654752f));
                if (MODE == 2) v += (float)res[(size_t)row * Ndim + col];
                store_val(&Y[(size_t)row * Ndim + col], v);
            }
        }
    }
}

// ---------------------------------------------------------------------------
// Flash attention w/ MFMA. Block = 64 q-rows x one (b,h); 4 waves, each owns
// 16 q-rows. Per 64-kv tile: QK^T (MFMA) + precomputed bias -> online softmax
// -> P through LDS -> PV (MFMA, V^T staged with XOR swizzle).
// Writes xpre = hin + ctx (f32).
// ---------------------------------------------------------------------------
__global__ __launch_bounds__(256) void attn_kernel(const f16* __restrict__ q,
                                                   const f16* __restrict__ k,
                                                   const f16* __restrict__ v,
                                                   const f16* __restrict__ bb,
                                                   const float* __restrict__ hin,
                                                   float* __restrict__ xpre) {
    __shared__ f16 sQ[64 * 72];
    __shared__ f16 sK[64 * 72];
    __shared__ f16 sVT[64 * 72];   // [d][m ^ 8*(d>>3&7)] swizzled
    __shared__ f16 sP[64 * 72];    // per-wave 16-row slabs

    const int t = threadIdx.x;
    const int w = t >> 6, lane = t & 63;
    const int lr = lane & 15, kq = lane >> 4;
    const int l0 = blockIdx.x * 64;
    const int h = blockIdx.y, b = blockIdx.z;
    const size_t base = (size_t)b * S_ * H_ + (size_t)h * DH_;

    // stage Q (pre-scaled by 1/sqrt(64))
    for (int idx = t; idx < 512; idx += 256) {
        int r = idx >> 3, c8 = (idx & 7) * 8;
        f16x8 qv = *(const f16x8*)&q[base + (size_t)(l0 + r) * H_ + c8];
#pragma unroll
        for (int e = 0; e < 8; e++) qv[e] = (f16)((float)qv[e] * 0.125f);
        *(f16x8*)&sQ[r * 72 + c8] = qv;
    }
    __syncthreads();
    f16x8 afq[2];
    afq[0] = *(const f16x8*)&sQ[(w * 16 + lr) * 72 + kq * 8];
    afq[1] = *(const f16x8*)&sQ[(w * 16 + lr) * 72 + 32 + kq * 8];

    f32x4 acc_o[4] = {};
    float mstate[4] = {-1e30f, -1e30f, -1e30f, -1e30f};
    float lstate[4] = {};

    for (int mt = 0; mt < 16; mt++) {
        const int m0 = mt * 64;
        __syncthreads();   // protect sK/sVT from previous iteration readers
        for (int idx = t; idx < 512; idx += 256) {
            int r = idx >> 3, c = idx & 7, c8 = c * 8;
            f16x8 kvv = *(const f16x8*)&k[base + (size_t)(m0 + r) * H_ + c8];
            *(f16x8*)&sK[r * 72 + c8] = kvv;
            f16x8 vv = *(const f16x8*)&v[base + (size_t)(m0 + r) * H_ + c8];
            int msw = r ^ c8;   // XOR swizzle (c8 = 8*(d>>3))
#pragma unroll
            for (int e = 0; e < 8; e++) sVT[(c8 + e) * 72 + msw] = vv[e];
        }
        __syncthreads();

        // ---- QK^T ----
        f32x4 sacc[4] = {};
#pragma unroll
        for (int ks = 0; ks < 2; ks++)
#pragma unroll
            for (int j = 0; j < 4; j++) {
                f16x8 bk = *(const f16x8*)&sK[(j * 16 + lr) * 72 + ks * 32 + kq * 8];
                sacc[j] = __builtin_amdgcn_mfma_f32_16x16x32_f16(afq[ks], bk, sacc[j], 0, 0, 0);
            }
        // ---- precomputed bias (tanh bilinear + mask) ----
        const f16* bbrow = bb + ((size_t)b * S_ + l0 + w * 16 + kq * 4) * S_ + m0;
#pragma unroll
        for (int j = 0; j < 4; j++)
#pragma unroll
            for (int rr = 0; rr < 4; rr++)
                sacc[j][rr] += (float)bbrow[(size_t)rr * S_ + j * 16 + lr];

        // ---- online softmax (row = l0 + 16w + 4kq + rr) ----
        float mnew[4], alpha[4], psum[4];
#pragma unroll
        for (int rr = 0; rr < 4; rr++) {
            float mx = fmaxf(fmaxf(sacc[0][rr], sacc[1][rr]), fmaxf(sacc[2][rr], sacc[3][rr]));
#pragma unroll
            for (int off = 8; off >= 1; off >>= 1) mx = fmaxf(mx, __shfl_xor(mx, off));
            mnew[rr] = fmaxf(mstate[rr], mx);
            alpha[rr] = expf(mstate[rr] - mnew[rr]);
            mstate[rr] = mnew[rr];
            psum[rr] = 0.f;
        }
#pragma unroll
        for (int j = 0; j < 4; j++)
#pragma unroll
            for (int rr = 0; rr < 4; rr++) {
                float p = expf(sacc[j][rr] - mnew[rr]);
                psum[rr] += p;
                sP[(w * 16 + kq * 4 + rr) * 72 + j * 16 + lr] = (f16)p;
            }
#pragma unroll
        for (int rr = 0; rr < 4; rr++) {
#pragma unroll
            for (int off = 8; off >= 1; off >>= 1) psum[rr] += __shfl_xor(psum[rr], off);
            lstate[rr] = lstate[rr] * alpha[rr] + psum[rr];
#pragma unroll
            for (int j = 0; j < 4; j++) acc_o[j][rr] *= alpha[rr];
        }
        __syncthreads();   // sP visible (cross-lane within wave; belt & braces)

        // ---- PV ----
        f16x8 ap[2];
        ap[0] = *(const f16x8*)&sP[(w * 16 + lr) * 72 + kq * 8];
        ap[1] = *(const f16x8*)&sP[(w * 16 + lr) * 72 + 32 + kq * 8];
#pragma unroll
        for (int ks = 0; ks < 2; ks++)
#pragma unroll
            for (int j2 = 0; j2 < 4; j2++) {
                int d = j2 * 16 + lr;
                int s_ = (d >> 3) & 7;
                f16x8 bv = *(const f16x8*)&sVT[d * 72 + 8 * (((ks << 2) + kq) ^ s_)];
                acc_o[j2] = __builtin_amdgcn_mfma_f32_16x16x32_f16(ap[ks], bv, acc_o[j2], 0, 0, 0);
            }
    }

    // ---- epilogue: xpre = hin + O/l ----
#pragma unroll
    for (int rr = 0; rr < 4; rr++) {
        float linv = 1.0f / lstate[rr];
        int tok = l0 + w * 16 + kq * 4 + rr;
        size_t obase = base + (size_t)tok * H_;
#pragma unroll
        for (int j2 = 0; j2 < 4; j2++) {
            int d = j2 * 16 + lr;
            xpre[obase + d] = hin[obase + d] + acc_o[j2][rr] * linv;
        }
    }
}

// ---------------------------------------------------------------------------
// LayerNorm over H=1280; one block per row. fp32 in, f16 out.
// ---------------------------------------------------------------------------
__global__ __launch_bounds__(256) void ln_kernel(const float* __restrict__ xpre,
                                                 const float* __restrict__ g,
                                                 const float* __restrict__ bb,
                                                 f16* __restrict__ xln) {
    int row = blockIdx.x, t = threadIdx.x;
    const float* xr = xpre + (size_t)row * H_;
    float xv[5], s1 = 0.f, s2 = 0.f;
#pragma unroll
    for (int i = 0; i < 5; i++) {
        float v = xr[t + 256 * i];
        xv[i] = v; s1 += v; s2 += v * v;
    }
#pragma unroll
    for (int o = 32; o >= 1; o >>= 1) { s1 += __shfl_xor(s1, o); s2 += __shfl_xor(s2, o); }
    __shared__ float r1[4], r2[4];
    int wv = t >> 6, lane = t & 63;
    if (lane == 0) { r1[wv] = s1; r2[wv] = s2; }
    __syncthreads();
    float m1 = (r1[0] + r1[1] + r1[2] + r1[3]) * (1.0f / H_);
    float m2 = (r2[0] + r2[1] + r2[2] + r2[3]) * (1.0f / H_);
    float rstd = rsqrtf(m2 - m1 * m1 + 1e-5f);
#pragma unroll
    for (int i = 0; i < 5; i++) {
        int c = t + 256 * i;
        float v = (xv[i] - m1) * rstd * g[c] + bb[c];
        xln[(size_t)row * H_ + c] = (f16)v;
    }
}

// ---------------------------------------------------------------------------
extern "C" void kernel_launch(void* const* d_in, const int* in_sizes, int n_in,
                              void* d_out, int out_size, void* d_ws, size_t ws_size,
                              hipStream_t stream) {
    (void)in_sizes; (void)n_in; (void)out_size; (void)ws_size;
    const float* hin  = (const float*)d_in[0];
    const float* mask = (const float*)d_in[1];
    const float* Wq = (const float*)d_in[2];  const float* bq = (const float*)d_in[3];
    const float* Wk = (const float*)d_in[4];  const float* bk = (const float*)d_in[5];
    const float* Wv = (const float*)d_in[6];  const float* bv = (const float*)d_in[7];
    const float* Wct1 = (const float*)d_in[8];  const float* bct1 = (const float*)d_in[9];
    const float* Wct2 = (const float*)d_in[10]; const float* bct2 = (const float*)d_in[11];
    const float* Mg = (const float*)d_in[12];   const float* bscale = (const float*)d_in[13];
    const float* Wptm = (const float*)d_in[14]; const float* bptm = (const float*)d_in[15];
    const float* lng = (const float*)d_in[16];  const float* lnb = (const float*)d_in[17];
    const float* Wf1 = (const float*)d_in[18];  const float* bf1 = (const float*)d_in[19];
    const float* Wf2 = (const float*)d_in[20];  const float* bf2 = (const float*)d_in[21];

    char* ws = (char*)d_ws;
    const size_t SZ_PT  = (size_t)B_ * S_ * P_ * 4;       // 131072
    const size_t SZ_H16 = (size_t)B_ * S_ * H_ * 2;       // 10485760 (f16)
    const size_t SZ_H32 = (size_t)B_ * S_ * H_ * 4;       // 20971520 (f32)
    float* Rg   = (float*)(ws);
    float* ptm  = (float*)(ws + 256);
    float* tg   = (float*)(ws + 256 + SZ_PT);
    char* A0    = ws + 256 + 2 * SZ_PT;
    f16* qb     = (f16*)(A0);
    f16* kb     = (f16*)(A0 + SZ_H16);
    f16* vb     = (f16*)(A0 + 2 * SZ_H16);
    float* xpre = (float*)(A0 + 3 * SZ_H16);
    f16* xln    = (f16*)(A0 + 3 * SZ_H16 + SZ_H32);
    f16* bbias  = (f16*)(A0 + 4 * SZ_H16 + SZ_H32);       // B*S*S f16 = 8.39 MB
    f16* g1     = (f16*)(A0);  // aliases qkv+xpre (dead by FFN1); 41.9MB < 52.4MB

    crosstalk_kernel<<<1, 128, 0, stream>>>(Mg, Wct1, bct1, Wct2, bct2, Rg);
    ptm_kernel<<<S_ * B_ / 4, 256, 0, stream>>>(hin, Wptm, bptm, Rg, ptm, tg);
    bias_kernel<<<B_ * S_, 256, 0, stream>>>(tg, ptm, mask, bscale, bbias);
    gemm_kernel<0, float, f16><<<dim3(64, 20), 256, 0, stream>>>(hin, Wq, bq, qb, nullptr, B_ * S_, H_, H_);
    gemm_kernel<0, float, f16><<<dim3(64, 20), 256, 0, stream>>>(hin, Wk, bk, kb, nullptr, B_ * S_, H_, H_);
    gemm_kernel<0, float, f16><<<dim3(64, 20), 256, 0, stream>>>(hin, Wv, bv, vb, nullptr, B_ * S_, H_, H_);
    attn_kernel<<<dim3(S_ / 64, NH_, B_), 256, 0, stream>>>(qb, kb, vb, bbias, hin, xpre);
    ln_kernel<<<B_ * S_, 256, 0, stream>>>(xpre, lng, lnb, xln);
    gemm_kernel<1, f16, f16><<<dim3(64, I_ / 64), 256, 0, stream>>>(xln, Wf1, bf1, g1, nullptr, B_ * S_, I_, H_);
    gemm_kernel<2, f16, float><<<dim3(64, 20), 256, 0, stream>>>(g1, Wf2, bf2, (float*)d_out, xln, B_ * S_, H_, I_);
}

// Round 4
// 516.558 us; speedup vs baseline: 6.9090x; 1.4397x over previous
//
#include <hip/hip_runtime.h>
#include <math.h>

typedef _Float16 f16;
typedef _Float16 f16x8 __attribute__((ext_vector_type(8)));
typedef _Float16 f16x4 __attribute__((ext_vector_type(4)));
typedef float f32x4 __attribute__((ext_vector_type(4)));

#define B_ 4
#define S_ 1024
#define H_ 1280
#define NH_ 20
#define DH_ 64
#define I_ 5120
#define C_ 13
#define P_ 8

__device__ __forceinline__ void store_val(float* p, float v) { *p = v; }
__device__ __forceinline__ void store_val(f16* p, float v) { *p = (f16)v; }

// ---------------------------------------------------------------------------
// f32 -> f16 bulk convert (vectorized), n4 = n/4
// ---------------------------------------------------------------------------
__global__ __launch_bounds__(256) void cvt_kernel(const float* __restrict__ src,
                                                  f16* __restrict__ dst, int n4) {
    int i = blockIdx.x * 256 + threadIdx.x;
    if (i < n4) {
        f32x4 v = ((const f32x4*)src)[i];
        f16x4 o;
#pragma unroll
        for (int e = 0; e < 4; e++) o[e] = (f16)v[e];
        ((f16x4*)dst)[i] = o;
    }
}

// ---------------------------------------------------------------------------
// Crosstalk: R = out1 @ out2  (8x8), tiny, one block
// ---------------------------------------------------------------------------
__global__ void crosstalk_kernel(const float* __restrict__ Mg,
                                 const float* __restrict__ W1, const float* __restrict__ b1,
                                 const float* __restrict__ W2, const float* __restrict__ b2,
                                 float* __restrict__ Rg) {
    __shared__ float o1[P_][C_];
    __shared__ float o2[C_][P_];
    int t = threadIdx.x;
    if (t < P_ * C_) {
        int p = t / C_, c = t % C_;
        float s = b1[p];
        for (int k = 0; k < C_; k++) s += Mg[k * C_ + c] * W1[p * C_ + k];
        o1[p][c] = s;
        int c2 = t / P_, p2 = t % P_;
        float s2 = b2[p2];
        for (int k = 0; k < C_; k++) s2 += Mg[c2 * C_ + k] * W2[p2 * C_ + k];
        o2[c2][p2] = s2;
    }
    __syncthreads();
    if (t < P_ * P_) {
        int p = t >> 3, q = t & 7;
        float s = 0.f;
        for (int c = 0; c < C_; c++) s += o1[p][c] * o2[c][q];
        Rg[t] = s;
    }
}

// ---------------------------------------------------------------------------
// ptm = softmax(h @ W_ptm^T + b_ptm); t = ptm @ R.  One wave per token row.
// ---------------------------------------------------------------------------
__global__ __launch_bounds__(256) void ptm_kernel(const float* __restrict__ hin,
                                                  const float* __restrict__ Wptm,
                                                  const float* __restrict__ bptm,
                                                  const float* __restrict__ Rg,
                                                  float* __restrict__ ptm,
                                                  float* __restrict__ tg) {
    int wv = threadIdx.x >> 6, lane = threadIdx.x & 63;
    int row = blockIdx.x * 4 + wv;
    const float* hrow = hin + (size_t)row * H_;
    float acc[P_] = {};
    for (int i = 0; i < H_ / 64; i++) {
        int k = lane + 64 * i;
        float hv = hrow[k];
#pragma unroll
        for (int p = 0; p < P_; p++) acc[p] += hv * Wptm[p * H_ + k];
    }
#pragma unroll
    for (int p = 0; p < P_; p++) {
#pragma unroll
        for (int o = 32; o >= 1; o >>= 1) acc[p] += __shfl_xor(acc[p], o);
        acc[p] += bptm[p];
    }
    float mx = acc[0];
#pragma unroll
    for (int p = 1; p < P_; p++) mx = fmaxf(mx, acc[p]);
    float sum = 0.f;
#pragma unroll
    for (int p = 0; p < P_; p++) { acc[p] = expf(acc[p] - mx); sum += acc[p]; }
    float rinv = 1.f / sum;
#pragma unroll
    for (int p = 0; p < P_; p++) acc[p] *= rinv;
    float tv[P_];
#pragma unroll
    for (int d = 0; d < P_; d++) {
        float s = 0.f;
#pragma unroll
        for (int c = 0; c < P_; c++) s += acc[c] * Rg[c * P_ + d];
        tv[d] = s;
    }
    if (lane == 0) {
#pragma unroll
        for (int p = 0; p < P_; p++) {
            ptm[(size_t)row * P_ + p] = acc[p];
            tg[(size_t)row * P_ + p]  = tv[p];
        }
    }
}

// ---------------------------------------------------------------------------
// Bias precompute: bb[b][l][m] = tanh(dot8(t[b,l], ptm[b,m]))*bscale
//                               + (1-mask[b,m])*(-30000)   (f16 out)
// ---------------------------------------------------------------------------
__global__ __launch_bounds__(256) void bias_kernel(const float* __restrict__ tg,
                                                   const float* __restrict__ ptm,
                                                   const float* __restrict__ mask,
                                                   const float* __restrict__ bscale_p,
                                                   f16* __restrict__ bb) {
    const int bl = blockIdx.x;          // b*1024 + l
    const int b = bl >> 10;
    const int t = threadIdx.x;
    __shared__ float tl[P_];
    if (t < P_) tl[t] = tg[(size_t)bl * P_ + t];
    __syncthreads();
    const float bscale = bscale_p[0];
    float t0 = tl[0], t1 = tl[1], t2 = tl[2], t3 = tl[3];
    float t4 = tl[4], t5 = tl[5], t6 = tl[6], t7 = tl[7];
#pragma unroll
    for (int i = 0; i < 4; i++) {
        int m = t + 256 * i;
        const float* pm = ptm + ((size_t)b * S_ + m) * P_;
        float4 p0 = *(const float4*)pm;
        float4 p1 = *(const float4*)(pm + 4);
        float d = t0 * p0.x + t1 * p0.y + t2 * p0.z + t3 * p0.w
                + t4 * p1.x + t5 * p1.y + t6 * p1.z + t7 * p1.w;
        float v = tanhf(d) * bscale + (1.0f - mask[(size_t)b * S_ + m]) * (-30000.0f);
        bb[(size_t)bl * S_ + m] = (f16)v;
    }
}

// ---------------------------------------------------------------------------
// m97-style GEMM body: 128x128 tile, BK=64, global_load_lds width=16,
// XOR-swizzled LDS (swizzle applied on global-address side, since
// global_load_lds forces linear LDS order). f16 inputs, f32 accumulate.
// MODE 0: plain f16 out. MODE 1: exact GELU. MODE 2: + residual, f32 out.
// ---------------------------------------------------------------------------
template <int MODE, typename YT>
__device__ __forceinline__ void gemm_body(const f16* __restrict__ X,
                                          const f16* __restrict__ W,
                                          const float* __restrict__ bias,
                                          YT* __restrict__ Y,
                                          const f16* __restrict__ res,
                                          int Ndim, int Kdim, int m0, int n0,
                                          f16* sA, f16* sB) {
    const int t = threadIdx.x;
    const int lane = t & 63, w = t >> 6;
    const int wr = w >> 1, wc = w & 1;
    const int lr = lane & 15, kq = lane >> 4;

    f32x4 acc[4][4] = {};

    // per-thread staging chunks: ci = t + 256*inst; LDS slot ci*16B (linear),
    // global k-group gc = (ci&7) ^ (row&7)  [row = ci>>3]
    int s_row[4], s_gc[4];
#pragma unroll
    for (int inst = 0; inst < 4; inst++) {
        int ci = t + 256 * inst;
        s_row[inst] = ci >> 3;
        s_gc[inst] = (ci & 7) ^ (s_row[inst] & 7);
    }

    for (int k0 = 0; k0 < Kdim; k0 += 64) {
        __syncthreads();   // previous tile's readers done (drains lgkmcnt)
#pragma unroll
        for (int inst = 0; inst < 4; inst++) {
            int ci = t + 256 * inst;
            __builtin_amdgcn_global_load_lds(
                (const unsigned*)(X + (size_t)(m0 + s_row[inst]) * Kdim + k0 + s_gc[inst] * 8),
                (unsigned*)(sA + ci * 8), 16, 0, 0);
        }
#pragma unroll
        for (int inst = 0; inst < 4; inst++) {
            int ci = t + 256 * inst;
            __builtin_amdgcn_global_load_lds(
                (const unsigned*)(W + (size_t)(n0 + s_row[inst]) * Kdim + k0 + s_gc[inst] * 8),
                (unsigned*)(sB + ci * 8), 16, 0, 0);
        }
        __syncthreads();   // drains vmcnt(0): staged data visible
#pragma unroll
        for (int ks = 0; ks < 2; ks++) {
            f16x8 af[4], bf[4];
#pragma unroll
            for (int i = 0; i < 4; i++) {
                int row = wr * 64 + i * 16 + lr;
                int cl = (ks * 4 + kq) ^ (row & 7);
                af[i] = *(const f16x8*)(sA + row * 64 + cl * 8);
            }
#pragma unroll
            for (int j = 0; j < 4; j++) {
                int row = wc * 64 + j * 16 + lr;
                int cl = (ks * 4 + kq) ^ (row & 7);
                bf[j] = *(const f16x8*)(sB + row * 64 + cl * 8);
            }
#pragma unroll
            for (int i = 0; i < 4; i++)
#pragma unroll
                for (int j = 0; j < 4; j++)
                    acc[i][j] = __builtin_amdgcn_mfma_f32_16x16x32_f16(af[i], bf[j], acc[i][j], 0, 0, 0);
        }
    }
    // epilogue: D col = lane&15, row = (lane>>4)*4 + reg
#pragma unroll
    for (int j = 0; j < 4; j++) {
        int col = n0 + wc * 64 + j * 16 + lr;
        float bcol = bias[col];
#pragma unroll
        for (int i = 0; i < 4; i++) {
#pragma unroll
            for (int rr = 0; rr < 4; rr++) {
                int row = m0 + wr * 64 + i * 16 + kq * 4 + rr;
                float v = acc[i][j][rr] + bcol;
                if (MODE == 1) v = 0.5f * v * (1.0f + erff(v * 0.70710678118654752f));
                if (MODE == 2) v += (float)res[(size_t)row * Ndim + col];
                store_val(&Y[(size_t)row * Ndim + col], v);
            }
        }
    }
}

template <int MODE, typename YT>
__global__ __launch_bounds__(256, 2) void gemm128(const f16* __restrict__ X,
                                                  const f16* __restrict__ W,
                                                  const float* __restrict__ bias,
                                                  YT* __restrict__ Y,
                                                  const f16* __restrict__ res,
                                                  int Ndim, int Kdim) {
    __shared__ f16 sA[128 * 64];
    __shared__ f16 sB[128 * 64];
    gemm_body<MODE, YT>(X, W, bias, Y, res, Ndim, Kdim,
                        blockIdx.x * 128, blockIdx.y * 128, sA, sB);
}

// Fused QKV: blockIdx.y in [0,30): group = y/10 selects {Q,K,V}, n-tile = y%10.
__global__ __launch_bounds__(256, 2) void gemm_qkv(const f16* __restrict__ X,
                                                   const f16* __restrict__ Wq,
                                                   const f16* __restrict__ Wk,
                                                   const f16* __restrict__ Wv,
                                                   const float* __restrict__ bq,
                                                   const float* __restrict__ bk,
                                                   const float* __restrict__ bv,
                                                   f16* __restrict__ qb,
                                                   f16* __restrict__ kb,
                                                   f16* __restrict__ vb) {
    __shared__ f16 sA[128 * 64];
    __shared__ f16 sB[128 * 64];
    const int g = blockIdx.y / 10, nt = blockIdx.y % 10;
    const f16* W = (g == 0) ? Wq : (g == 1) ? Wk : Wv;
    const float* bias = (g == 0) ? bq : (g == 1) ? bk : bv;
    f16* Y = (g == 0) ? qb : (g == 1) ? kb : vb;
    gemm_body<0, f16>(X, W, bias, Y, nullptr, H_, H_,
                      blockIdx.x * 128, nt * 128, sA, sB);
}

// ---------------------------------------------------------------------------
// Flash attention w/ MFMA (unchanged from round 3).
// ---------------------------------------------------------------------------
__global__ __launch_bounds__(256) void attn_kernel(const f16* __restrict__ q,
                                                   const f16* __restrict__ k,
                                                   const f16* __restrict__ v,
                                                   const f16* __restrict__ bb,
                                                   const float* __restrict__ hin,
                                                   float* __restrict__ xpre) {
    __shared__ f16 sQ[64 * 72];
    __shared__ f16 sK[64 * 72];
    __shared__ f16 sVT[64 * 72];   // [d][m ^ 8*(d>>3&7)] swizzled
    __shared__ f16 sP[64 * 72];

    const int t = threadIdx.x;
    const int w = t >> 6, lane = t & 63;
    const int lr = lane & 15, kq = lane >> 4;
    const int l0 = blockIdx.x * 64;
    const int h = blockIdx.y, b = blockIdx.z;
    const size_t base = (size_t)b * S_ * H_ + (size_t)h * DH_;

    for (int idx = t; idx < 512; idx += 256) {
        int r = idx >> 3, c8 = (idx & 7) * 8;
        f16x8 qv = *(const f16x8*)&q[base + (size_t)(l0 + r) * H_ + c8];
#pragma unroll
        for (int e = 0; e < 8; e++) qv[e] = (f16)((float)qv[e] * 0.125f);
        *(f16x8*)&sQ[r * 72 + c8] = qv;
    }
    __syncthreads();
    f16x8 afq[2];
    afq[0] = *(const f16x8*)&sQ[(w * 16 + lr) * 72 + kq * 8];
    afq[1] = *(const f16x8*)&sQ[(w * 16 + lr) * 72 + 32 + kq * 8];

    f32x4 acc_o[4] = {};
    float mstate[4] = {-1e30f, -1e30f, -1e30f, -1e30f};
    float lstate[4] = {};

    for (int mt = 0; mt < 16; mt++) {
        const int m0 = mt * 64;
        __syncthreads();
        for (int idx = t; idx < 512; idx += 256) {
            int r = idx >> 3, c = idx & 7, c8 = c * 8;
            f16x8 kvv = *(const f16x8*)&k[base + (size_t)(m0 + r) * H_ + c8];
            *(f16x8*)&sK[r * 72 + c8] = kvv;
            f16x8 vv = *(const f16x8*)&v[base + (size_t)(m0 + r) * H_ + c8];
            int msw = r ^ c8;
#pragma unroll
            for (int e = 0; e < 8; e++) sVT[(c8 + e) * 72 + msw] = vv[e];
        }
        __syncthreads();

        f32x4 sacc[4] = {};
#pragma unroll
        for (int ks = 0; ks < 2; ks++)
#pragma unroll
            for (int j = 0; j < 4; j++) {
                f16x8 bk = *(const f16x8*)&sK[(j * 16 + lr) * 72 + ks * 32 + kq * 8];
                sacc[j] = __builtin_amdgcn_mfma_f32_16x16x32_f16(afq[ks], bk, sacc[j], 0, 0, 0);
            }
        const f16* bbrow = bb + ((size_t)b * S_ + l0 + w * 16 + kq * 4) * S_ + m0;
#pragma unroll
        for (int j = 0; j < 4; j++)
#pragma unroll
            for (int rr = 0; rr < 4; rr++)
                sacc[j][rr] += (float)bbrow[(size_t)rr * S_ + j * 16 + lr];

        float mnew[4], alpha[4], psum[4];
#pragma unroll
        for (int rr = 0; rr < 4; rr++) {
            float mx = fmaxf(fmaxf(sacc[0][rr], sacc[1][rr]), fmaxf(sacc[2][rr], sacc[3][rr]));
#pragma unroll
            for (int off = 8; off >= 1; off >>= 1) mx = fmaxf(mx, __shfl_xor(mx, off));
            mnew[rr] = fmaxf(mstate[rr], mx);
            alpha[rr] = expf(mstate[rr] - mnew[rr]);
            mstate[rr] = mnew[rr];
            psum[rr] = 0.f;
        }
#pragma unroll
        for (int j = 0; j < 4; j++)
#pragma unroll
            for (int rr = 0; rr < 4; rr++) {
                float p = expf(sacc[j][rr] - mnew[rr]);
                psum[rr] += p;
                sP[(w * 16 + kq * 4 + rr) * 72 + j * 16 + lr] = (f16)p;
            }
#pragma unroll
        for (int rr = 0; rr < 4; rr++) {
#pragma unroll
            for (int off = 8; off >= 1; off >>= 1) psum[rr] += __shfl_xor(psum[rr], off);
            lstate[rr] = lstate[rr] * alpha[rr] + psum[rr];
#pragma unroll
            for (int j = 0; j < 4; j++) acc_o[j][rr] *= alpha[rr];
        }
        __syncthreads();

        f16x8 ap[2];
        ap[0] = *(const f16x8*)&sP[(w * 16 + lr) * 72 + kq * 8];
        ap[1] = *(const f16x8*)&sP[(w * 16 + lr) * 72 + 32 + kq * 8];
#pragma unroll
        for (int ks = 0; ks < 2; ks++)
#pragma unroll
            for (int j2 = 0; j2 < 4; j2++) {
                int d = j2 * 16 + lr;
                int s_ = (d >> 3) & 7;
                f16x8 bv = *(const f16x8*)&sVT[d * 72 + 8 * (((ks << 2) + kq) ^ s_)];
                acc_o[j2] = __builtin_amdgcn_mfma_f32_16x16x32_f16(ap[ks], bv, acc_o[j2], 0, 0, 0);
            }
    }

#pragma unroll
    for (int rr = 0; rr < 4; rr++) {
        float linv = 1.0f / lstate[rr];
        int tok = l0 + w * 16 + kq * 4 + rr;
        size_t obase = base + (size_t)tok * H_;
#pragma unroll
        for (int j2 = 0; j2 < 4; j2++) {
            int d = j2 * 16 + lr;
            xpre[obase + d] = hin[obase + d] + acc_o[j2][rr] * linv;
        }
    }
}

// ---------------------------------------------------------------------------
// LayerNorm over H=1280; one block per row. fp32 in, f16 out.
// ---------------------------------------------------------------------------
__global__ __launch_bounds__(256) void ln_kernel(const float* __restrict__ xpre,
                                                 const float* __restrict__ g,
                                                 const float* __restrict__ bb,
                                                 f16* __restrict__ xln) {
    int row = blockIdx.x, t = threadIdx.x;
    const float* xr = xpre + (size_t)row * H_;
    float xv[5], s1 = 0.f, s2 = 0.f;
#pragma unroll
    for (int i = 0; i < 5; i++) {
        float v = xr[t + 256 * i];
        xv[i] = v; s1 += v; s2 += v * v;
    }
#pragma unroll
    for (int o = 32; o >= 1; o >>= 1) { s1 += __shfl_xor(s1, o); s2 += __shfl_xor(s2, o); }
    __shared__ float r1[4], r2[4];
    int wv = t >> 6, lane = t & 63;
    if (lane == 0) { r1[wv] = s1; r2[wv] = s2; }
    __syncthreads();
    float m1 = (r1[0] + r1[1] + r1[2] + r1[3]) * (1.0f / H_);
    float m2 = (r2[0] + r2[1] + r2[2] + r2[3]) * (1.0f / H_);
    float rstd = rsqrtf(m2 - m1 * m1 + 1e-5f);
#pragma unroll
    for (int i = 0; i < 5; i++) {
        int c = t + 256 * i;
        float v = (xv[i] - m1) * rstd * g[c] + bb[c];
        xln[(size_t)row * H_ + c] = (f16)v;
    }
}

// ---------------------------------------------------------------------------
extern "C" void kernel_launch(void* const* d_in, const int* in_sizes, int n_in,
                              void* d_out, int out_size, void* d_ws, size_t ws_size,
                              hipStream_t stream) {
    (void)in_sizes; (void)n_in; (void)out_size; (void)ws_size;
    const float* hin  = (const float*)d_in[0];
    const float* mask = (const float*)d_in[1];
    const float* Wq = (const float*)d_in[2];  const float* bq = (const float*)d_in[3];
    const float* Wk = (const float*)d_in[4];  const float* bk = (const float*)d_in[5];
    const float* Wv = (const float*)d_in[6];  const float* bv = (const float*)d_in[7];
    const float* Wct1 = (const float*)d_in[8];  const float* bct1 = (const float*)d_in[9];
    const float* Wct2 = (const float*)d_in[10]; const float* bct2 = (const float*)d_in[11];
    const float* Mg = (const float*)d_in[12];   const float* bscale = (const float*)d_in[13];
    const float* Wptm = (const float*)d_in[14]; const float* bptm = (const float*)d_in[15];
    const float* lng = (const float*)d_in[16];  const float* lnb = (const float*)d_in[17];
    const float* Wf1 = (const float*)d_in[18];  const float* bf1 = (const float*)d_in[19];
    const float* Wf2 = (const float*)d_in[20];  const float* bf2 = (const float*)d_in[21];

    char* ws = (char*)d_ws;
    const size_t SZ_PT  = (size_t)B_ * S_ * P_ * 4;       // 131072
    const size_t SZ_H16 = (size_t)B_ * S_ * H_ * 2;       // 10485760 (f16)
    const size_t SZ_H32 = (size_t)B_ * S_ * H_ * 4;       // 20971520 (f32)
    const size_t SZ_WH  = (size_t)H_ * H_ * 2;            // 3276800  (1280x1280 f16)
    const size_t SZ_WI  = (size_t)I_ * H_ * 2;            // 13107200 (5120x1280 f16)
    float* Rg   = (float*)(ws);
    float* ptm  = (float*)(ws + 256);
    float* tg   = (float*)(ws + 256 + SZ_PT);
    char* A0    = ws + 256 + 2 * SZ_PT;
    f16* hin16  = (f16*)(A0);
    f16* qb     = (f16*)(A0 + SZ_H16);
    f16* kb     = (f16*)(A0 + 2 * SZ_H16);
    f16* vb     = (f16*)(A0 + 3 * SZ_H16);
    float* xpre = (float*)(A0 + 4 * SZ_H16);
    f16* xln    = (f16*)(A0 + 4 * SZ_H16 + SZ_H32);
    f16* bbias  = (f16*)(A0 + 5 * SZ_H16 + SZ_H32);       // 8.39 MB
    char* WA    = A0 + 5 * SZ_H16 + SZ_H32 + (size_t)B_ * S_ * S_ * 2;
    f16* Wq16   = (f16*)(WA);
    f16* Wk16   = (f16*)(WA + SZ_WH);
    f16* Wv16   = (f16*)(WA + 2 * SZ_WH);
    f16* Wf116  = (f16*)(WA + 3 * SZ_WH);
    f16* Wf216  = (f16*)(WA + 3 * SZ_WH + SZ_WI);
    f16* g1     = (f16*)(A0);   // 41.9 MB, aliases hin16+qkv (62.9 MB dead by FFN1)
    // peak ~125 MB

    const int NH4 = (B_ * S_ * H_) / 4, NW4 = (H_ * H_) / 4, NI4 = (I_ * H_) / 4;
    cvt_kernel<<<(NH4 + 255) / 256, 256, 0, stream>>>(hin, hin16, NH4);
    cvt_kernel<<<(NW4 + 255) / 256, 256, 0, stream>>>(Wq, Wq16, NW4);
    cvt_kernel<<<(NW4 + 255) / 256, 256, 0, stream>>>(Wk, Wk16, NW4);
    cvt_kernel<<<(NW4 + 255) / 256, 256, 0, stream>>>(Wv, Wv16, NW4);
    cvt_kernel<<<(NI4 + 255) / 256, 256, 0, stream>>>(Wf1, Wf116, NI4);
    cvt_kernel<<<(NI4 + 255) / 256, 256, 0, stream>>>(Wf2, Wf216, NI4);

    crosstalk_kernel<<<1, 128, 0, stream>>>(Mg, Wct1, bct1, Wct2, bct2, Rg);
    ptm_kernel<<<S_ * B_ / 4, 256, 0, stream>>>(hin, Wptm, bptm, Rg, ptm, tg);
    bias_kernel<<<B_ * S_, 256, 0, stream>>>(tg, ptm, mask, bscale, bbias);
    gemm_qkv<<<dim3(32, 30), 256, 0, stream>>>(hin16, Wq16, Wk16, Wv16, bq, bk, bv, qb, kb, vb);
    attn_kernel<<<dim3(S_ / 64, NH_, B_), 256, 0, stream>>>(qb, kb, vb, bbias, hin, xpre);
    ln_kernel<<<B_ * S_, 256, 0, stream>>>(xpre, lng, lnb, xln);
    gemm128<1, f16><<<dim3(32, I_ / 128), 256, 0, stream>>>(xln, Wf116, bf1, g1, nullptr, I_, H_);
    gemm128<2, float><<<dim3(32, 10), 256, 0, stream>>>(g1, Wf216, bf2, (float*)d_out, xln, H_, I_);
}

// Round 5
// 494.293 us; speedup vs baseline: 7.2202x; 1.0450x over previous
//
#include <hip/hip_runtime.h>
#include <math.h>

typedef _Float16 f16;
typedef _Float16 f16x2 __attribute__((ext_vector_type(2)));
typedef _Float16 f16x8 __attribute__((ext_vector_type(8)));
typedef _Float16 f16x4 __attribute__((ext_vector_type(4)));
typedef float f32x4 __attribute__((ext_vector_type(4)));

#define B_ 4
#define S_ 1024
#define H_ 1280
#define NH_ 20
#define DH_ 64
#define I_ 5120
#define C_ 13
#define P_ 8
#define LOG2E 1.44269504088896f

__device__ __forceinline__ void store_val(float* p, float v) { *p = v; }
__device__ __forceinline__ void store_val(f16* p, float v) { *p = (f16)v; }

// ---------------------------------------------------------------------------
// Fused f32 -> f16 bulk convert: 6 segments in one launch (blockIdx.y = seg)
// ---------------------------------------------------------------------------
__global__ __launch_bounds__(256) void cvt6_kernel(
    const float* __restrict__ s0, f16* __restrict__ d0, int n0,
    const float* __restrict__ s1, f16* __restrict__ d1, int n1,
    const float* __restrict__ s2, f16* __restrict__ d2, int n2,
    const float* __restrict__ s3, f16* __restrict__ d3, int n3,
    const float* __restrict__ s4, f16* __restrict__ d4, int n4,
    const float* __restrict__ s5, f16* __restrict__ d5, int n5) {
    int seg = blockIdx.y;
    const float* src = (seg == 0) ? s0 : (seg == 1) ? s1 : (seg == 2) ? s2
                     : (seg == 3) ? s3 : (seg == 4) ? s4 : s5;
    f16* dst = (seg == 0) ? d0 : (seg == 1) ? d1 : (seg == 2) ? d2
             : (seg == 3) ? d3 : (seg == 4) ? d4 : d5;
    int n = (seg == 0) ? n0 : (seg == 1) ? n1 : (seg == 2) ? n2
          : (seg == 3) ? n3 : (seg == 4) ? n4 : n5;
    int i = blockIdx.x * 256 + threadIdx.x;
    if (i < n) {
        f32x4 v = ((const f32x4*)src)[i];
        f16x4 o;
#pragma unroll
        for (int e = 0; e < 4; e++) o[e] = (f16)v[e];
        ((f16x4*)dst)[i] = o;
    }
}

// ---------------------------------------------------------------------------
// Crosstalk: R = out1 @ out2  (8x8), tiny, one block
// ---------------------------------------------------------------------------
__global__ void crosstalk_kernel(const float* __restrict__ Mg,
                                 const float* __restrict__ W1, const float* __restrict__ b1,
                                 const float* __restrict__ W2, const float* __restrict__ b2,
                                 float* __restrict__ Rg) {
    __shared__ float o1[P_][C_];
    __shared__ float o2[C_][P_];
    int t = threadIdx.x;
    if (t < P_ * C_) {
        int p = t / C_, c = t % C_;
        float s = b1[p];
        for (int k = 0; k < C_; k++) s += Mg[k * C_ + c] * W1[p * C_ + k];
        o1[p][c] = s;
        int c2 = t / P_, p2 = t % P_;
        float s2 = b2[p2];
        for (int k = 0; k < C_; k++) s2 += Mg[c2 * C_ + k] * W2[p2 * C_ + k];
        o2[c2][p2] = s2;
    }
    __syncthreads();
    if (t < P_ * P_) {
        int p = t >> 3, q = t & 7;
        float s = 0.f;
        for (int c = 0; c < C_; c++) s += o1[p][c] * o2[c][q];
        Rg[t] = s;
    }
}

// ---------------------------------------------------------------------------
// ptm = softmax(h @ W_ptm^T + b_ptm); t = ptm @ R.  One wave per token row.
// ---------------------------------------------------------------------------
__global__ __launch_bounds__(256) void ptm_kernel(const float* __restrict__ hin,
                                                  const float* __restrict__ Wptm,
                                                  const float* __restrict__ bptm,
                                                  const float* __restrict__ Rg,
                                                  float* __restrict__ ptm,
                                                  float* __restrict__ tg) {
    int wv = threadIdx.x >> 6, lane = threadIdx.x & 63;
    int row = blockIdx.x * 4 + wv;
    const float* hrow = hin + (size_t)row * H_;
    float acc[P_] = {};
    for (int i = 0; i < H_ / 64; i++) {
        int k = lane + 64 * i;
        float hv = hrow[k];
#pragma unroll
        for (int p = 0; p < P_; p++) acc[p] += hv * Wptm[p * H_ + k];
    }
#pragma unroll
    for (int p = 0; p < P_; p++) {
#pragma unroll
        for (int o = 32; o >= 1; o >>= 1) acc[p] += __shfl_xor(acc[p], o);
        acc[p] += bptm[p];
    }
    float mx = acc[0];
#pragma unroll
    for (int p = 1; p < P_; p++) mx = fmaxf(mx, acc[p]);
    float sum = 0.f;
#pragma unroll
    for (int p = 0; p < P_; p++) { acc[p] = expf(acc[p] - mx); sum += acc[p]; }
    float rinv = 1.f / sum;
#pragma unroll
    for (int p = 0; p < P_; p++) acc[p] *= rinv;
    float tv[P_];
#pragma unroll
    for (int d = 0; d < P_; d++) {
        float s = 0.f;
#pragma unroll
        for (int c = 0; c < P_; c++) s += acc[c] * Rg[c * P_ + d];
        tv[d] = s;
    }
    if (lane == 0) {
#pragma unroll
        for (int p = 0; p < P_; p++) {
            ptm[(size_t)row * P_ + p] = acc[p];
            tg[(size_t)row * P_ + p]  = tv[p];
        }
    }
}

// ---------------------------------------------------------------------------
// Bias precompute, LOG2E-folded: bb = (tanh(dot8)*bscale + maskterm) * LOG2E
// ---------------------------------------------------------------------------
__global__ __launch_bounds__(256) void bias_kernel(const float* __restrict__ tg,
                                                   const float* __restrict__ ptm,
                                                   const float* __restrict__ mask,
                                                   const float* __restrict__ bscale_p,
                                                   f16* __restrict__ bb) {
    const int bl = blockIdx.x;          // b*1024 + l
    const int b = bl >> 10;
    const int t = threadIdx.x;
    __shared__ float tl[P_];
    if (t < P_) tl[t] = tg[(size_t)bl * P_ + t];
    __syncthreads();
    const float bscale = bscale_p[0];
    float t0 = tl[0], t1 = tl[1], t2 = tl[2], t3 = tl[3];
    float t4 = tl[4], t5 = tl[5], t6 = tl[6], t7 = tl[7];
#pragma unroll
    for (int i = 0; i < 4; i++) {
        int m = t + 256 * i;
        const float* pm = ptm + ((size_t)b * S_ + m) * P_;
        float4 p0 = *(const float4*)pm;
        float4 p1 = *(const float4*)(pm + 4);
        float d = t0 * p0.x + t1 * p0.y + t2 * p0.z + t3 * p0.w
                + t4 * p1.x + t5 * p1.y + t6 * p1.z + t7 * p1.w;
        float v = (tanhf(d) * bscale + (1.0f - mask[(size_t)b * S_ + m]) * (-30000.0f)) * LOG2E;
        bb[(size_t)bl * S_ + m] = (f16)v;
    }
}

// ---------------------------------------------------------------------------
// m97-style GEMM body: 128x128 tile, BK=64, global_load_lds width=16,
// XOR swizzle on the global-address side. f16 in, f32 accumulate.
// MODE 0: plain f16 out. MODE 1: exact GELU. MODE 2: + residual, f32 out.
// ---------------------------------------------------------------------------
template <int MODE, typename YT>
__device__ __forceinline__ void gemm_body(const f16* __restrict__ X,
                                          const f16* __restrict__ W,
                                          const float* __restrict__ bias,
                                          YT* __restrict__ Y,
                                          const f16* __restrict__ res,
                                          int Ndim, int Kdim, int m0, int n0,
                                          f16* sA, f16* sB) {
    const int t = threadIdx.x;
    const int lane = t & 63, w = t >> 6;
    const int wr = w >> 1, wc = w & 1;
    const int lr = lane & 15, kq = lane >> 4;

    f32x4 acc[4][4] = {};

    int s_row[4], s_gc[4];
#pragma unroll
    for (int inst = 0; inst < 4; inst++) {
        int ci = t + 256 * inst;
        s_row[inst] = ci >> 3;
        s_gc[inst] = (ci & 7) ^ (s_row[inst] & 7);
    }

    for (int k0 = 0; k0 < Kdim; k0 += 64) {
        __syncthreads();
#pragma unroll
        for (int inst = 0; inst < 4; inst++) {
            int ci = t + 256 * inst;
            __builtin_amdgcn_global_load_lds(
                (const unsigned*)(X + (size_t)(m0 + s_row[inst]) * Kdim + k0 + s_gc[inst] * 8),
                (unsigned*)(sA + ci * 8), 16, 0, 0);
        }
#pragma unroll
        for (int inst = 0; inst < 4; inst++) {
            int ci = t + 256 * inst;
            __builtin_amdgcn_global_load_lds(
                (const unsigned*)(W + (size_t)(n0 + s_row[inst]) * Kdim + k0 + s_gc[inst] * 8),
                (unsigned*)(sB + ci * 8), 16, 0, 0);
        }
        __syncthreads();
#pragma unroll
        for (int ks = 0; ks < 2; ks++) {
            f16x8 af[4], bf[4];
#pragma unroll
            for (int i = 0; i < 4; i++) {
                int row = wr * 64 + i * 16 + lr;
                int cl = (ks * 4 + kq) ^ (row & 7);
                af[i] = *(const f16x8*)(sA + row * 64 + cl * 8);
            }
#pragma unroll
            for (int j = 0; j < 4; j++) {
                int row = wc * 64 + j * 16 + lr;
                int cl = (ks * 4 + kq) ^ (row & 7);
                bf[j] = *(const f16x8*)(sB + row * 64 + cl * 8);
            }
#pragma unroll
            for (int i = 0; i < 4; i++)
#pragma unroll
                for (int j = 0; j < 4; j++)
                    acc[i][j] = __builtin_amdgcn_mfma_f32_16x16x32_f16(af[i], bf[j], acc[i][j], 0, 0, 0);
        }
    }
#pragma unroll
    for (int j = 0; j < 4; j++) {
        int col = n0 + wc * 64 + j * 16 + lr;
        float bcol = bias[col];
#pragma unroll
        for (int i = 0; i < 4; i++) {
#pragma unroll
            for (int rr = 0; rr < 4; rr++) {
                int row = m0 + wr * 64 + i * 16 + kq * 4 + rr;
                float v = acc[i][j][rr] + bcol;
                if (MODE == 1) v = 0.5f * v * (1.0f + erff(v * 0.70710678118654752f));
                if (MODE == 2) v += (float)res[(size_t)row * Ndim + col];
                store_val(&Y[(size_t)row * Ndim + col], v);
            }
        }
    }
}

template <int MODE, typename YT>
__global__ __launch_bounds__(256, 2) void gemm128(const f16* __restrict__ X,
                                                  const f16* __restrict__ W,
                                                  const float* __restrict__ bias,
                                                  YT* __restrict__ Y,
                                                  const f16* __restrict__ res,
                                                  int Ndim, int Kdim) {
    __shared__ f16 sA[128 * 64];
    __shared__ f16 sB[128 * 64];
    gemm_body<MODE, YT>(X, W, bias, Y, res, Ndim, Kdim,
                        blockIdx.x * 128, blockIdx.y * 128, sA, sB);
}

__global__ __launch_bounds__(256, 2) void gemm_qkv(const f16* __restrict__ X,
                                                   const f16* __restrict__ Wq,
                                                   const f16* __restrict__ Wk,
                                                   const f16* __restrict__ Wv,
                                                   const float* __restrict__ bq,
                                                   const float* __restrict__ bk,
                                                   const float* __restrict__ bv,
                                                   f16* __restrict__ qb,
                                                   f16* __restrict__ kb,
                                                   f16* __restrict__ vb) {
    __shared__ f16 sA[128 * 64];
    __shared__ f16 sB[128 * 64];
    const int g = blockIdx.y / 10, nt = blockIdx.y % 10;
    const f16* W = (g == 0) ? Wq : (g == 1) ? Wk : Wv;
    const float* bias = (g == 0) ? bq : (g == 1) ? bk : bv;
    f16* Y = (g == 0) ? qb : (g == 1) ? kb : vb;
    gemm_body<0, f16>(X, W, bias, Y, nullptr, H_, H_,
                      blockIdx.x * 128, nt * 128, sA, sB);
}

// ---------------------------------------------------------------------------
// Flash attention w/ MFMA, no-max exp2 softmax (scores log2-domain: Q scale
// and bias carry LOG2E). Row-sum accumulated per-lane, reduced once at end.
// ---------------------------------------------------------------------------
__global__ __launch_bounds__(256) void attn_kernel(const f16* __restrict__ q,
                                                   const f16* __restrict__ k,
                                                   const f16* __restrict__ v,
                                                   const f16* __restrict__ bb,
                                                   const float* __restrict__ hin,
                                                   float* __restrict__ xpre) {
    __shared__ f16 sQ[64 * 72];
    __shared__ f16 sK[64 * 72];
    __shared__ f16 sVT[64 * 72];   // [d][m ^ 8*(d>>3&7)] swizzled
    __shared__ f16 sP[64 * 72];

    const int t = threadIdx.x;
    const int w = t >> 6, lane = t & 63;
    const int lr = lane & 15, kq = lane >> 4;
    const int l0 = blockIdx.x * 64;
    const int h = blockIdx.y, b = blockIdx.z;
    const size_t base = (size_t)b * S_ * H_ + (size_t)h * DH_;

    // stage Q, scaled by (1/8)*log2(e): scores come out in log2 domain
    for (int idx = t; idx < 512; idx += 256) {
        int r = idx >> 3, c8 = (idx & 7) * 8;
        f16x8 qv = *(const f16x8*)&q[base + (size_t)(l0 + r) * H_ + c8];
#pragma unroll
        for (int e = 0; e < 8; e++) qv[e] = (f16)((float)qv[e] * (0.125f * LOG2E));
        *(f16x8*)&sQ[r * 72 + c8] = qv;
    }
    __syncthreads();
    f16x8 afq[2];
    afq[0] = *(const f16x8*)&sQ[(w * 16 + lr) * 72 + kq * 8];
    afq[1] = *(const f16x8*)&sQ[(w * 16 + lr) * 72 + 32 + kq * 8];

    f32x4 acc_o[4] = {};
    float lstate[4] = {};

    // V pair-staging indices: 32 row-pairs x 8 chunks = 256 = one per thread
    const int vr2 = (t >> 3) * 2, vc8 = (t & 7) * 8;
    const int vmsw = vr2 ^ vc8;

    for (int mt = 0; mt < 16; mt++) {
        const int m0 = mt * 64;
        __syncthreads();
        for (int idx = t; idx < 512; idx += 256) {
            int r = idx >> 3, c8 = (idx & 7) * 8;
            f16x8 kvv = *(const f16x8*)&k[base + (size_t)(m0 + r) * H_ + c8];
            *(f16x8*)&sK[r * 72 + c8] = kvv;
        }
        {
            f16x8 v0 = *(const f16x8*)&v[base + (size_t)(m0 + vr2) * H_ + vc8];
            f16x8 v1 = *(const f16x8*)&v[base + (size_t)(m0 + vr2 + 1) * H_ + vc8];
#pragma unroll
            for (int e = 0; e < 8; e++) {
                f16x2 pk = {v0[e], v1[e]};
                *(f16x2*)&sVT[(vc8 + e) * 72 + vmsw] = pk;   // even index: 4B aligned
            }
        }
        __syncthreads();

        // ---- QK^T (log2 domain) ----
        f32x4 sacc[4] = {};
#pragma unroll
        for (int ks = 0; ks < 2; ks++)
#pragma unroll
            for (int j = 0; j < 4; j++) {
                f16x8 bk = *(const f16x8*)&sK[(j * 16 + lr) * 72 + ks * 32 + kq * 8];
                sacc[j] = __builtin_amdgcn_mfma_f32_16x16x32_f16(afq[ks], bk, sacc[j], 0, 0, 0);
            }
        // ---- bias (already LOG2E-scaled) ----
        const f16* bbrow = bb + ((size_t)b * S_ + l0 + w * 16 + kq * 4) * S_ + m0;
#pragma unroll
        for (int j = 0; j < 4; j++)
#pragma unroll
            for (int rr = 0; rr < 4; rr++)
                sacc[j][rr] += (float)bbrow[(size_t)rr * S_ + j * 16 + lr];

        // ---- p = 2^s, accumulate row-sum per lane, stash P to LDS ----
#pragma unroll
        for (int j = 0; j < 4; j++)
#pragma unroll
            for (int rr = 0; rr < 4; rr++) {
                float p = __builtin_exp2f(sacc[j][rr]);
                lstate[rr] += p;
                sP[(w * 16 + kq * 4 + rr) * 72 + j * 16 + lr] = (f16)p;
            }
        __syncthreads();

        // ---- PV ----
        f16x8 ap[2];
        ap[0] = *(const f16x8*)&sP[(w * 16 + lr) * 72 + kq * 8];
        ap[1] = *(const f16x8*)&sP[(w * 16 + lr) * 72 + 32 + kq * 8];
#pragma unroll
        for (int ks = 0; ks < 2; ks++)
#pragma unroll
            for (int j2 = 0; j2 < 4; j2++) {
                int d = j2 * 16 + lr;
                int s_ = (d >> 3) & 7;
                f16x8 bv = *(const f16x8*)&sVT[d * 72 + 8 * (((ks << 2) + kq) ^ s_)];
                acc_o[j2] = __builtin_amdgcn_mfma_f32_16x16x32_f16(ap[ks], bv, acc_o[j2], 0, 0, 0);
            }
    }

    // ---- final row-sum reduction across the 16 lanes of the kq-group ----
#pragma unroll
    for (int rr = 0; rr < 4; rr++) {
#pragma unroll
        for (int off = 8; off >= 1; off >>= 1) lstate[rr] += __shfl_xor(lstate[rr], off);
    }

    // ---- epilogue: xpre = hin + O/l ----
#pragma unroll
    for (int rr = 0; rr < 4; rr++) {
        float linv = 1.0f / lstate[rr];
        int tok = l0 + w * 16 + kq * 4 + rr;
        size_t obase = base + (size_t)tok * H_;
#pragma unroll
        for (int j2 = 0; j2 < 4; j2++) {
            int d = j2 * 16 + lr;
            xpre[obase + d] = hin[obase + d] + acc_o[j2][rr] * linv;
        }
    }
}

// ---------------------------------------------------------------------------
// LayerNorm over H=1280; one block per row. fp32 in, f16 out.
// ---------------------------------------------------------------------------
__global__ __launch_bounds__(256) void ln_kernel(const float* __restrict__ xpre,
                                                 const float* __restrict__ g,
                                                 const float* __restrict__ bb,
                                                 f16* __restrict__ xln) {
    int row = blockIdx.x, t = threadIdx.x;
    const float* xr = xpre + (size_t)row * H_;
    float xv[5], s1 = 0.f, s2 = 0.f;
#pragma unroll
    for (int i = 0; i < 5; i++) {
        float v = xr[t + 256 * i];
        xv[i] = v; s1 += v; s2 += v * v;
    }
#pragma unroll
    for (int o = 32; o >= 1; o >>= 1) { s1 += __shfl_xor(s1, o); s2 += __shfl_xor(s2, o); }
    __shared__ float r1[4], r2[4];
    int wv = t >> 6, lane = t & 63;
    if (lane == 0) { r1[wv] = s1; r2[wv] = s2; }
    __syncthreads();
    float m1 = (r1[0] + r1[1] + r1[2] + r1[3]) * (1.0f / H_);
    float m2 = (r2[0] + r2[1] + r2[2] + r2[3]) * (1.0f / H_);
    float rstd = rsqrtf(m2 - m1 * m1 + 1e-5f);
#pragma unroll
    for (int i = 0; i < 5; i++) {
        int c = t + 256 * i;
        float v = (xv[i] - m1) * rstd * g[c] + bb[c];
        xln[(size_t)row * H_ + c] = (f16)v;
    }
}

// ---------------------------------------------------------------------------
extern "C" void kernel_launch(void* const* d_in, const int* in_sizes, int n_in,
                              void* d_out, int out_size, void* d_ws, size_t ws_size,
                              hipStream_t stream) {
    (void)in_sizes; (void)n_in; (void)out_size; (void)ws_size;
    const float* hin  = (const float*)d_in[0];
    const float* mask = (const float*)d_in[1];
    const float* Wq = (const float*)d_in[2];  const float* bq = (const float*)d_in[3];
    const float* Wk = (const float*)d_in[4];  const float* bk = (const float*)d_in[5];
    const float* Wv = (const float*)d_in[6];  const float* bv = (const float*)d_in[7];
    const float* Wct1 = (const float*)d_in[8];  const float* bct1 = (const float*)d_in[9];
    const float* Wct2 = (const float*)d_in[10]; const float* bct2 = (const float*)d_in[11];
    const float* Mg = (const float*)d_in[12];   const float* bscale = (const float*)d_in[13];
    const float* Wptm = (const float*)d_in[14]; const float* bptm = (const float*)d_in[15];
    const float* lng = (const float*)d_in[16];  const float* lnb = (const float*)d_in[17];
    const float* Wf1 = (const float*)d_in[18];  const float* bf1 = (const float*)d_in[19];
    const float* Wf2 = (const float*)d_in[20];  const float* bf2 = (const float*)d_in[21];

    char* ws = (char*)d_ws;
    const size_t SZ_PT  = (size_t)B_ * S_ * P_ * 4;       // 131072
    const size_t SZ_H16 = (size_t)B_ * S_ * H_ * 2;       // 10485760 (f16)
    const size_t SZ_H32 = (size_t)B_ * S_ * H_ * 4;       // 20971520 (f32)
    const size_t SZ_WH  = (size_t)H_ * H_ * 2;            // 3276800
    const size_t SZ_WI  = (size_t)I_ * H_ * 2;            // 13107200
    float* Rg   = (float*)(ws);
    float* ptm  = (float*)(ws + 256);
    float* tg   = (float*)(ws + 256 + SZ_PT);
    char* A0    = ws + 256 + 2 * SZ_PT;
    f16* hin16  = (f16*)(A0);
    f16* qb     = (f16*)(A0 + SZ_H16);
    f16* kb     = (f16*)(A0 + 2 * SZ_H16);
    f16* vb     = (f16*)(A0 + 3 * SZ_H16);
    float* xpre = (float*)(A0 + 4 * SZ_H16);
    f16* xln    = (f16*)(A0 + 4 * SZ_H16 + SZ_H32);
    f16* bbias  = (f16*)(A0 + 5 * SZ_H16 + SZ_H32);       // 8.39 MB
    char* WA    = A0 + 5 * SZ_H16 + SZ_H32 + (size_t)B_ * S_ * S_ * 2;
    f16* Wq16   = (f16*)(WA);
    f16* Wk16   = (f16*)(WA + SZ_WH);
    f16* Wv16   = (f16*)(WA + 2 * SZ_WH);
    f16* Wf116  = (f16*)(WA + 3 * SZ_WH);
    f16* Wf216  = (f16*)(WA + 3 * SZ_WH + SZ_WI);
    f16* g1     = (f16*)(A0);   // aliases hin16+qkv (dead by FFN1)

    const int NH4 = (B_ * S_ * H_) / 4, NW4 = (H_ * H_) / 4, NI4 = (I_ * H_) / 4;
    cvt6_kernel<<<dim3((NI4 + 255) / 256, 6), 256, 0, stream>>>(
        hin, hin16, NH4, Wq, Wq16, NW4, Wk, Wk16, NW4,
        Wv, Wv16, NW4, Wf1, Wf116, NI4, Wf2, Wf216, NI4);

    crosstalk_kernel<<<1, 128, 0, stream>>>(Mg, Wct1, bct1, Wct2, bct2, Rg);
    ptm_kernel<<<S_ * B_ / 4, 256, 0, stream>>>(hin, Wptm, bptm, Rg, ptm, tg);
    bias_kernel<<<B_ * S_, 256, 0, stream>>>(tg, ptm, mask, bscale, bbias);
    gemm_qkv<<<dim3(32, 30), 256, 0, stream>>>(hin16, Wq16, Wk16, Wv16, bq, bk, bv, qb, kb, vb);
    attn_kernel<<<dim3(S_ / 64, NH_, B_), 256, 0, stream>>>(qb, kb, vb, bbias, hin, xpre);
    ln_kernel<<<B_ * S_, 256, 0, stream>>>(xpre, lng, lnb, xln);
    gemm128<1, f16><<<dim3(32, I_ / 128), 256, 0, stream>>>(xln, Wf116, bf1, g1, nullptr, I_, H_);
    gemm128<2, float><<<dim3(32, 10), 256, 0, stream>>>(g1, Wf216, bf2, (float*)d_out, xln, H_, I_);
}

// Round 6
// 465.656 us; speedup vs baseline: 7.6642x; 1.0615x over previous
//
#include <hip/hip_runtime.h>
#include <math.h>

typedef _Float16 f16;
typedef _Float16 f16x2 __attribute__((ext_vector_type(2)));
typedef _Float16 f16x8 __attribute__((ext_vector_type(8)));
typedef _Float16 f16x4 __attribute__((ext_vector_type(4)));
typedef float f32x4 __attribute__((ext_vector_type(4)));

#define B_ 4
#define S_ 1024
#define H_ 1280
#define NH_ 20
#define DH_ 64
#define I_ 5120
#define C_ 13
#define P_ 8
#define LOG2E 1.44269504088896f

__device__ __forceinline__ void store_val(float* p, float v) { *p = v; }
__device__ __forceinline__ void store_val(f16* p, float v) { *p = (f16)v; }

// ---------------------------------------------------------------------------
// Fused f32 -> f16 bulk convert: 6 segments in one launch (blockIdx.y = seg)
// ---------------------------------------------------------------------------
__global__ __launch_bounds__(256) void cvt6_kernel(
    const float* __restrict__ s0, f16* __restrict__ d0, int n0,
    const float* __restrict__ s1, f16* __restrict__ d1, int n1,
    const float* __restrict__ s2, f16* __restrict__ d2, int n2,
    const float* __restrict__ s3, f16* __restrict__ d3, int n3,
    const float* __restrict__ s4, f16* __restrict__ d4, int n4,
    const float* __restrict__ s5, f16* __restrict__ d5, int n5) {
    int seg = blockIdx.y;
    const float* src = (seg == 0) ? s0 : (seg == 1) ? s1 : (seg == 2) ? s2
                     : (seg == 3) ? s3 : (seg == 4) ? s4 : s5;
    f16* dst = (seg == 0) ? d0 : (seg == 1) ? d1 : (seg == 2) ? d2
             : (seg == 3) ? d3 : (seg == 4) ? d4 : d5;
    int n = (seg == 0) ? n0 : (seg == 1) ? n1 : (seg == 2) ? n2
          : (seg == 3) ? n3 : (seg == 4) ? n4 : n5;
    int i = blockIdx.x * 256 + threadIdx.x;
    if (i < n) {
        f32x4 v = ((const f32x4*)src)[i];
        f16x4 o;
#pragma unroll
        for (int e = 0; e < 4; e++) o[e] = (f16)v[e];
        ((f16x4*)dst)[i] = o;
    }
}

// ---------------------------------------------------------------------------
// ptm = softmax(h @ W_ptm^T + b_ptm); t = ptm @ R.  One wave per token row.
// Crosstalk R (8x8) folded in: recomputed per block (trivial, inputs cached).
// ---------------------------------------------------------------------------
__global__ __launch_bounds__(256) void ptm_kernel(const float* __restrict__ hin,
                                                  const float* __restrict__ Wptm,
                                                  const float* __restrict__ bptm,
                                                  const float* __restrict__ Mg,
                                                  const float* __restrict__ W1,
                                                  const float* __restrict__ b1,
                                                  const float* __restrict__ W2,
                                                  const float* __restrict__ b2,
                                                  float* __restrict__ ptm,
                                                  float* __restrict__ tg) {
    __shared__ float o1[P_][C_];
    __shared__ float o2[C_][P_];
    __shared__ float R[P_ * P_];
    int t = threadIdx.x;
    if (t < P_ * C_) {
        int p = t / C_, c = t % C_;
        float s = b1[p];
        for (int k = 0; k < C_; k++) s += Mg[k * C_ + c] * W1[p * C_ + k];
        o1[p][c] = s;
        int c2 = t / P_, p2 = t % P_;
        float s2 = b2[p2];
        for (int k = 0; k < C_; k++) s2 += Mg[c2 * C_ + k] * W2[p2 * C_ + k];
        o2[c2][p2] = s2;
    }
    __syncthreads();
    if (t < P_ * P_) {
        int p = t >> 3, q = t & 7;
        float s = 0.f;
        for (int c = 0; c < C_; c++) s += o1[p][c] * o2[c][q];
        R[t] = s;
    }
    __syncthreads();

    int wv = t >> 6, lane = t & 63;
    int row = blockIdx.x * 4 + wv;
    const float* hrow = hin + (size_t)row * H_;
    float acc[P_] = {};
    for (int i = 0; i < H_ / 64; i++) {
        int k = lane + 64 * i;
        float hv = hrow[k];
#pragma unroll
        for (int p = 0; p < P_; p++) acc[p] += hv * Wptm[p * H_ + k];
    }
#pragma unroll
    for (int p = 0; p < P_; p++) {
#pragma unroll
        for (int o = 32; o >= 1; o >>= 1) acc[p] += __shfl_xor(acc[p], o);
        acc[p] += bptm[p];
    }
    float mx = acc[0];
#pragma unroll
    for (int p = 1; p < P_; p++) mx = fmaxf(mx, acc[p]);
    float sum = 0.f;
#pragma unroll
    for (int p = 0; p < P_; p++) { acc[p] = expf(acc[p] - mx); sum += acc[p]; }
    float rinv = 1.f / sum;
#pragma unroll
    for (int p = 0; p < P_; p++) acc[p] *= rinv;
    float tv[P_];
#pragma unroll
    for (int d = 0; d < P_; d++) {
        float s = 0.f;
#pragma unroll
        for (int c = 0; c < P_; c++) s += acc[c] * R[c * P_ + d];
        tv[d] = s;
    }
    if (lane == 0) {
#pragma unroll
        for (int p = 0; p < P_; p++) {
            ptm[(size_t)row * P_ + p] = acc[p];
            tg[(size_t)row * P_ + p]  = tv[p];
        }
    }
}

// ---------------------------------------------------------------------------
// Bias precompute, LOG2E-folded: bb = (tanh(dot8)*bscale + maskterm) * LOG2E
// ---------------------------------------------------------------------------
__global__ __launch_bounds__(256) void bias_kernel(const float* __restrict__ tg,
                                                   const float* __restrict__ ptm,
                                                   const float* __restrict__ mask,
                                                   const float* __restrict__ bscale_p,
                                                   f16* __restrict__ bb) {
    const int bl = blockIdx.x;          // b*1024 + l
    const int b = bl >> 10;
    const int t = threadIdx.x;
    __shared__ float tl[P_];
    if (t < P_) tl[t] = tg[(size_t)bl * P_ + t];
    __syncthreads();
    const float bscale = bscale_p[0];
    float t0 = tl[0], t1 = tl[1], t2 = tl[2], t3 = tl[3];
    float t4 = tl[4], t5 = tl[5], t6 = tl[6], t7 = tl[7];
#pragma unroll
    for (int i = 0; i < 4; i++) {
        int m = t + 256 * i;
        const float* pm = ptm + ((size_t)b * S_ + m) * P_;
        float4 p0 = *(const float4*)pm;
        float4 p1 = *(const float4*)(pm + 4);
        float d = t0 * p0.x + t1 * p0.y + t2 * p0.z + t3 * p0.w
                + t4 * p1.x + t5 * p1.y + t6 * p1.z + t7 * p1.w;
        float v = (tanhf(d) * bscale + (1.0f - mask[(size_t)b * S_ + m]) * (-30000.0f)) * LOG2E;
        bb[(size_t)bl * S_ + m] = (f16)v;
    }
}

// ---------------------------------------------------------------------------
// m97-style GEMM body: 128x128 tile, BK=64, global_load_lds width=16,
// XOR swizzle on the global-address side. f16 in, f32 accumulate.
// MODE 0: plain f16 out. MODE 1: exact GELU. MODE 2: + residual, f32 out.
// MODE 3: raw f32 partial (no bias/res) for split-K.
// ---------------------------------------------------------------------------
template <int MODE, typename YT>
__device__ __forceinline__ void gemm_body(const f16* __restrict__ X,
                                          const f16* __restrict__ W,
                                          const float* __restrict__ bias,
                                          YT* __restrict__ Y,
                                          const f16* __restrict__ res,
                                          int Ndim, int Kdim, int kbeg, int kend,
                                          int m0, int n0, f16* sA, f16* sB) {
    const int t = threadIdx.x;
    const int lane = t & 63, w = t >> 6;
    const int wr = w >> 1, wc = w & 1;
    const int lr = lane & 15, kq = lane >> 4;

    f32x4 acc[4][4] = {};

    int s_row[4], s_gc[4];
#pragma unroll
    for (int inst = 0; inst < 4; inst++) {
        int ci = t + 256 * inst;
        s_row[inst] = ci >> 3;
        s_gc[inst] = (ci & 7) ^ (s_row[inst] & 7);
    }

    for (int k0 = kbeg; k0 < kend; k0 += 64) {
        __syncthreads();
#pragma unroll
        for (int inst = 0; inst < 4; inst++) {
            int ci = t + 256 * inst;
            __builtin_amdgcn_global_load_lds(
                (const unsigned*)(X + (size_t)(m0 + s_row[inst]) * Kdim + k0 + s_gc[inst] * 8),
                (unsigned*)(sA + ci * 8), 16, 0, 0);
        }
#pragma unroll
        for (int inst = 0; inst < 4; inst++) {
            int ci = t + 256 * inst;
            __builtin_amdgcn_global_load_lds(
                (const unsigned*)(W + (size_t)(n0 + s_row[inst]) * Kdim + k0 + s_gc[inst] * 8),
                (unsigned*)(sB + ci * 8), 16, 0, 0);
        }
        __syncthreads();
#pragma unroll
        for (int ks = 0; ks < 2; ks++) {
            f16x8 af[4], bf[4];
#pragma unroll
            for (int i = 0; i < 4; i++) {
                int row = wr * 64 + i * 16 + lr;
                int cl = (ks * 4 + kq) ^ (row & 7);
                af[i] = *(const f16x8*)(sA + row * 64 + cl * 8);
            }
#pragma unroll
            for (int j = 0; j < 4; j++) {
                int row = wc * 64 + j * 16 + lr;
                int cl = (ks * 4 + kq) ^ (row & 7);
                bf[j] = *(const f16x8*)(sB + row * 64 + cl * 8);
            }
#pragma unroll
            for (int i = 0; i < 4; i++)
#pragma unroll
                for (int j = 0; j < 4; j++)
                    acc[i][j] = __builtin_amdgcn_mfma_f32_16x16x32_f16(af[i], bf[j], acc[i][j], 0, 0, 0);
        }
    }
#pragma unroll
    for (int j = 0; j < 4; j++) {
        int col = n0 + wc * 64 + j * 16 + lr;
        float bcol = (MODE == 3) ? 0.f : bias[col];
#pragma unroll
        for (int i = 0; i < 4; i++) {
#pragma unroll
            for (int rr = 0; rr < 4; rr++) {
                int row = m0 + wr * 64 + i * 16 + kq * 4 + rr;
                float v = acc[i][j][rr] + bcol;
                if (MODE == 1) v = 0.5f * v * (1.0f + erff(v * 0.70710678118654752f));
                if (MODE == 2) v += (float)res[(size_t)row * Ndim + col];
                store_val(&Y[(size_t)row * Ndim + col], v);
            }
        }
    }
}

template <int MODE, typename YT>
__global__ __launch_bounds__(256, 2) void gemm128(const f16* __restrict__ X,
                                                  const f16* __restrict__ W,
                                                  const float* __restrict__ bias,
                                                  YT* __restrict__ Y,
                                                  const f16* __restrict__ res,
                                                  int Ndim, int Kdim) {
    __shared__ f16 sA[128 * 64];
    __shared__ f16 sB[128 * 64];
    gemm_body<MODE, YT>(X, W, bias, Y, res, Ndim, Kdim, 0, Kdim,
                        blockIdx.x * 128, blockIdx.y * 128, sA, sB);
}

// Split-K=2 partial GEMM: blockIdx.z picks K-half; writes raw f32 partial.
__global__ __launch_bounds__(256, 2) void gemm_sk(const f16* __restrict__ X,
                                                  const f16* __restrict__ W,
                                                  float* __restrict__ Pb,
                                                  int Ndim, int Kdim, int Mdim) {
    __shared__ f16 sA[128 * 64];
    __shared__ f16 sB[128 * 64];
    const int kd2 = Kdim >> 1;
    float* Y = Pb + (size_t)blockIdx.z * Mdim * Ndim;
    gemm_body<3, float>(X, W, nullptr, Y, nullptr, Ndim, Kdim,
                        blockIdx.z * kd2, blockIdx.z * kd2 + kd2,
                        blockIdx.x * 128, blockIdx.y * 128, sA, sB);
}

// Split-K reduce: out = p0 + p1 + bias[col] + res(f16), float4-vectorized.
__global__ __launch_bounds__(256) void reduce2_kernel(const float* __restrict__ p0,
                                                      const float* __restrict__ p1,
                                                      const float* __restrict__ bias,
                                                      const f16* __restrict__ res,
                                                      float* __restrict__ out) {
    int i = blockIdx.x * 256 + threadIdx.x;       // float4 index
    int col = (i * 4) % H_;                       // H_ % 4 == 0: no row crossing
    f32x4 a = ((const f32x4*)p0)[i];
    f32x4 b = ((const f32x4*)p1)[i];
    f32x4 bc = *(const f32x4*)(bias + col);
    f16x4 r = ((const f16x4*)res)[i];
    f32x4 o;
#pragma unroll
    for (int e = 0; e < 4; e++) o[e] = a[e] + b[e] + bc[e] + (float)r[e];
    ((f32x4*)out)[i] = o;
}

__global__ __launch_bounds__(256, 2) void gemm_qkv(const f16* __restrict__ X,
                                                   const f16* __restrict__ Wq,
                                                   const f16* __restrict__ Wk,
                                                   const f16* __restrict__ Wv,
                                                   const float* __restrict__ bq,
                                                   const float* __restrict__ bk,
                                                   const float* __restrict__ bv,
                                                   f16* __restrict__ qb,
                                                   f16* __restrict__ kb,
                                                   f16* __restrict__ vb) {
    __shared__ f16 sA[128 * 64];
    __shared__ f16 sB[128 * 64];
    const int g = blockIdx.y / 10, nt = blockIdx.y % 10;
    const f16* W = (g == 0) ? Wq : (g == 1) ? Wk : Wv;
    const float* bias = (g == 0) ? bq : (g == 1) ? bk : bv;
    f16* Y = (g == 0) ? qb : (g == 1) ? kb : vb;
    gemm_body<0, f16>(X, W, bias, Y, nullptr, H_, H_, 0, H_,
                      blockIdx.x * 128, nt * 128, sA, sB);
}

// ---------------------------------------------------------------------------
// Flash attention w/ MFMA, no-max exp2 softmax (log2-domain scores).
// ---------------------------------------------------------------------------
__global__ __launch_bounds__(256) void attn_kernel(const f16* __restrict__ q,
                                                   const f16* __restrict__ k,
                                                   const f16* __restrict__ v,
                                                   const f16* __restrict__ bb,
                                                   const float* __restrict__ hin,
                                                   float* __restrict__ xpre) {
    __shared__ f16 sQ[64 * 72];
    __shared__ f16 sK[64 * 72];
    __shared__ f16 sVT[64 * 72];   // [d][m ^ 8*(d>>3&7)] swizzled
    __shared__ f16 sP[64 * 72];

    const int t = threadIdx.x;
    const int w = t >> 6, lane = t & 63;
    const int lr = lane & 15, kq = lane >> 4;
    const int l0 = blockIdx.x * 64;
    const int h = blockIdx.y, b = blockIdx.z;
    const size_t base = (size_t)b * S_ * H_ + (size_t)h * DH_;

    for (int idx = t; idx < 512; idx += 256) {
        int r = idx >> 3, c8 = (idx & 7) * 8;
        f16x8 qv = *(const f16x8*)&q[base + (size_t)(l0 + r) * H_ + c8];
#pragma unroll
        for (int e = 0; e < 8; e++) qv[e] = (f16)((float)qv[e] * (0.125f * LOG2E));
        *(f16x8*)&sQ[r * 72 + c8] = qv;
    }
    __syncthreads();
    f16x8 afq[2];
    afq[0] = *(const f16x8*)&sQ[(w * 16 + lr) * 72 + kq * 8];
    afq[1] = *(const f16x8*)&sQ[(w * 16 + lr) * 72 + 32 + kq * 8];

    f32x4 acc_o[4] = {};
    float lstate[4] = {};

    const int vr2 = (t >> 3) * 2, vc8 = (t & 7) * 8;
    const int vmsw = vr2 ^ vc8;

    for (int mt = 0; mt < 16; mt++) {
        const int m0 = mt * 64;
        __syncthreads();
        for (int idx = t; idx < 512; idx += 256) {
            int r = idx >> 3, c8 = (idx & 7) * 8;
            f16x8 kvv = *(const f16x8*)&k[base + (size_t)(m0 + r) * H_ + c8];
            *(f16x8*)&sK[r * 72 + c8] = kvv;
        }
        {
            f16x8 v0 = *(const f16x8*)&v[base + (size_t)(m0 + vr2) * H_ + vc8];
            f16x8 v1 = *(const f16x8*)&v[base + (size_t)(m0 + vr2 + 1) * H_ + vc8];
#pragma unroll
            for (int e = 0; e < 8; e++) {
                f16x2 pk = {v0[e], v1[e]};
                *(f16x2*)&sVT[(vc8 + e) * 72 + vmsw] = pk;
            }
        }
        __syncthreads();

        f32x4 sacc[4] = {};
#pragma unroll
        for (int ks = 0; ks < 2; ks++)
#pragma unroll
            for (int j = 0; j < 4; j++) {
                f16x8 bk = *(const f16x8*)&sK[(j * 16 + lr) * 72 + ks * 32 + kq * 8];
                sacc[j] = __builtin_amdgcn_mfma_f32_16x16x32_f16(afq[ks], bk, sacc[j], 0, 0, 0);
            }
        const f16* bbrow = bb + ((size_t)b * S_ + l0 + w * 16 + kq * 4) * S_ + m0;
#pragma unroll
        for (int j = 0; j < 4; j++)
#pragma unroll
            for (int rr = 0; rr < 4; rr++)
                sacc[j][rr] += (float)bbrow[(size_t)rr * S_ + j * 16 + lr];

#pragma unroll
        for (int j = 0; j < 4; j++)
#pragma unroll
            for (int rr = 0; rr < 4; rr++) {
                float p = __builtin_exp2f(sacc[j][rr]);
                lstate[rr] += p;
                sP[(w * 16 + kq * 4 + rr) * 72 + j * 16 + lr] = (f16)p;
            }
        __syncthreads();

        f16x8 ap[2];
        ap[0] = *(const f16x8*)&sP[(w * 16 + lr) * 72 + kq * 8];
        ap[1] = *(const f16x8*)&sP[(w * 16 + lr) * 72 + 32 + kq * 8];
#pragma unroll
        for (int ks = 0; ks < 2; ks++)
#pragma unroll
            for (int j2 = 0; j2 < 4; j2++) {
                int d = j2 * 16 + lr;
                int s_ = (d >> 3) & 7;
                f16x8 bv = *(const f16x8*)&sVT[d * 72 + 8 * (((ks << 2) + kq) ^ s_)];
                acc_o[j2] = __builtin_amdgcn_mfma_f32_16x16x32_f16(ap[ks], bv, acc_o[j2], 0, 0, 0);
            }
    }

#pragma unroll
    for (int rr = 0; rr < 4; rr++) {
#pragma unroll
        for (int off = 8; off >= 1; off >>= 1) lstate[rr] += __shfl_xor(lstate[rr], off);
    }

#pragma unroll
    for (int rr = 0; rr < 4; rr++) {
        float linv = 1.0f / lstate[rr];
        int tok = l0 + w * 16 + kq * 4 + rr;
        size_t obase = base + (size_t)tok * H_;
#pragma unroll
        for (int j2 = 0; j2 < 4; j2++) {
            int d = j2 * 16 + lr;
            xpre[obase + d] = hin[obase + d] + acc_o[j2][rr] * linv;
        }
    }
}

// ---------------------------------------------------------------------------
// LayerNorm over H=1280; one block per row. fp32 in, f16 out.
// ---------------------------------------------------------------------------
__global__ __launch_bounds__(256) void ln_kernel(const float* __restrict__ xpre,
                                                 const float* __restrict__ g,
                                                 const float* __restrict__ bb,
                                                 f16* __restrict__ xln) {
    int row = blockIdx.x, t = threadIdx.x;
    const float* xr = xpre + (size_t)row * H_;
    float xv[5], s1 = 0.f, s2 = 0.f;
#pragma unroll
    for (int i = 0; i < 5; i++) {
        float v = xr[t + 256 * i];
        xv[i] = v; s1 += v; s2 += v * v;
    }
#pragma unroll
    for (int o = 32; o >= 1; o >>= 1) { s1 += __shfl_xor(s1, o); s2 += __shfl_xor(s2, o); }
    __shared__ float r1[4], r2[4];
    int wv = t >> 6, lane = t & 63;
    if (lane == 0) { r1[wv] = s1; r2[wv] = s2; }
    __syncthreads();
    float m1 = (r1[0] + r1[1] + r1[2] + r1[3]) * (1.0f / H_);
    float m2 = (r2[0] + r2[1] + r2[2] + r2[3]) * (1.0f / H_);
    float rstd = rsqrtf(m2 - m1 * m1 + 1e-5f);
#pragma unroll
    for (int i = 0; i < 5; i++) {
        int c = t + 256 * i;
        float v = (xv[i] - m1) * rstd * g[c] + bb[c];
        xln[(size_t)row * H_ + c] = (f16)v;
    }
}

// ---------------------------------------------------------------------------
extern "C" void kernel_launch(void* const* d_in, const int* in_sizes, int n_in,
                              void* d_out, int out_size, void* d_ws, size_t ws_size,
                              hipStream_t stream) {
    (void)in_sizes; (void)n_in; (void)out_size; (void)ws_size;
    const float* hin  = (const float*)d_in[0];
    const float* mask = (const float*)d_in[1];
    const float* Wq = (const float*)d_in[2];  const float* bq = (const float*)d_in[3];
    const float* Wk = (const float*)d_in[4];  const float* bk = (const float*)d_in[5];
    const float* Wv = (const float*)d_in[6];  const float* bv = (const float*)d_in[7];
    const float* Wct1 = (const float*)d_in[8];  const float* bct1 = (const float*)d_in[9];
    const float* Wct2 = (const float*)d_in[10]; const float* bct2 = (const float*)d_in[11];
    const float* Mg = (const float*)d_in[12];   const float* bscale = (const float*)d_in[13];
    const float* Wptm = (const float*)d_in[14]; const float* bptm = (const float*)d_in[15];
    const float* lng = (const float*)d_in[16];  const float* lnb = (const float*)d_in[17];
    const float* Wf1 = (const float*)d_in[18];  const float* bf1 = (const float*)d_in[19];
    const float* Wf2 = (const float*)d_in[20];  const float* bf2 = (const float*)d_in[21];

    char* ws = (char*)d_ws;
    const size_t SZ_PT  = (size_t)B_ * S_ * P_ * 4;       // 131072
    const size_t SZ_H16 = (size_t)B_ * S_ * H_ * 2;       // 10485760 (f16)
    const size_t SZ_H32 = (size_t)B_ * S_ * H_ * 4;       // 20971520 (f32)
    const size_t SZ_WH  = (size_t)H_ * H_ * 2;            // 3276800
    const size_t SZ_WI  = (size_t)I_ * H_ * 2;            // 13107200
    float* ptm  = (float*)(ws + 256);
    float* tg   = (float*)(ws + 256 + SZ_PT);
    char* A0    = ws + 256 + 2 * SZ_PT;
    f16* hin16  = (f16*)(A0);
    f16* qb     = (f16*)(A0 + SZ_H16);
    f16* kb     = (f16*)(A0 + 2 * SZ_H16);
    f16* vb     = (f16*)(A0 + 3 * SZ_H16);
    float* xpre = (float*)(A0 + 4 * SZ_H16);
    f16* xln    = (f16*)(A0 + 4 * SZ_H16 + SZ_H32);
    f16* bbias  = (f16*)(A0 + 5 * SZ_H16 + SZ_H32);       // 8.39 MB
    char* WA    = A0 + 5 * SZ_H16 + SZ_H32 + (size_t)B_ * S_ * S_ * 2;
    f16* Wq16   = (f16*)(WA);
    f16* Wk16   = (f16*)(WA + SZ_WH);
    f16* Wv16   = (f16*)(WA + 2 * SZ_WH);
    f16* Wf116  = (f16*)(WA + 3 * SZ_WH);
    f16* Wf216  = (f16*)(WA + 3 * SZ_WH + SZ_WI);
    f16* g1     = (f16*)(A0);                  // aliases hin16+qkv (dead by FFN1)
    float* pbuf = (float*)(WA + 3 * SZ_WH + 2 * SZ_WI);   // 2 x 21.0 MB partials
    // peak ~161 MB

    const int NH4 = (B_ * S_ * H_) / 4, NW4 = (H_ * H_) / 4, NI4 = (I_ * H_) / 4;
    cvt6_kernel<<<dim3((NI4 + 255) / 256, 6), 256, 0, stream>>>(
        hin, hin16, NH4, Wq, Wq16, NW4, Wk, Wk16, NW4,
        Wv, Wv16, NW4, Wf1, Wf116, NI4, Wf2, Wf216, NI4);

    ptm_kernel<<<S_ * B_ / 4, 256, 0, stream>>>(hin, Wptm, bptm,
                                                Mg, Wct1, bct1, Wct2, bct2, ptm, tg);
    bias_kernel<<<B_ * S_, 256, 0, stream>>>(tg, ptm, mask, bscale, bbias);
    gemm_qkv<<<dim3(32, 30), 256, 0, stream>>>(hin16, Wq16, Wk16, Wv16, bq, bk, bv, qb, kb, vb);
    attn_kernel<<<dim3(S_ / 64, NH_, B_), 256, 0, stream>>>(qb, kb, vb, bbias, hin, xpre);
    ln_kernel<<<B_ * S_, 256, 0, stream>>>(xpre, lng, lnb, xln);
    gemm128<1, f16><<<dim3(32, I_ / 128), 256, 0, stream>>>(xln, Wf116, bf1, g1, nullptr, I_, H_);
    // FFN2 split-K=2: 640 blocks (vs 320) -> 2+ blocks/CU co-resident
    gemm_sk<<<dim3(32, 10, 2), 256, 0, stream>>>(g1, Wf216, pbuf, H_, I_, B_ * S_);
    reduce2_kernel<<<(B_ * S_ * H_) / 4 / 256, 256, 0, stream>>>(
        pbuf, pbuf + (size_t)B_ * S_ * H_, bf2, xln, (float*)d_out);
}